// Round 1
// baseline (470.163 us; speedup 1.0000x reference)
//
#include <hip/hip_runtime.h>
#include <hip/hip_bf16.h>
#include <stdint.h>

#define BATCH 4
#define SEQ   4096
#define DIM   2048
#define NFREQ 1025
#define NCPLX 1024
#define ROWS  (BATCH*SEQ)   // 16384

// scan decomposition
#define SCH 256            // s-chunk length
#define NSC (SEQ/SCH)      // 16 chunks
#define FCB 5              // ceil(1025/256) freq-column blocks

typedef __bf16 bf16x8 __attribute__((ext_vector_type(8)));
typedef float  f32x4  __attribute__((ext_vector_type(4)));

__device__ __forceinline__ unsigned bitrev10(unsigned x) { return __brev(x) >> 22; }

__device__ __forceinline__ unsigned short f2bf(float f) {
  union { float f; unsigned u; } v; v.f = f;
  unsigned r = v.u + 0x7fffu + ((v.u >> 16) & 1u);
  return (unsigned short)(r >> 16);
}

// ---------------- forward rfft (packed-real, 1024-pt complex DIT) -------------
__global__ __launch_bounds__(256) void fft_fwd(const float* __restrict__ x,
                                               float2* __restrict__ xhat) {
  __shared__ float2 z[NCPLX];
  const int row = blockIdx.x;
  const int tid = threadIdx.x;
  const float* xr = x + (size_t)row * DIM;
#pragma unroll
  for (int i = 0; i < 4; i++) {
    int n = tid + 256*i;
    float2 v = *(const float2*)(xr + 2*n);   // z[n] = x[2n] + i x[2n+1]
    z[bitrev10(n)] = v;
  }
  __syncthreads();
#pragma unroll
  for (int s = 1; s <= 10; s++) {
    const int half = 1 << (s-1);
#pragma unroll
    for (int bi = 0; bi < 2; bi++) {
      int b  = tid + 256*bi;                 // butterfly 0..511
      int j  = b & (half-1);
      int i0 = ((b >> (s-1)) << s) + j;
      int i1 = i0 + half;
      float ang = -3.14159265358979323846f * (float)j / (float)half;
      float sw, cw; __sincosf(ang, &sw, &cw);
      float2 u = z[i0], v = z[i1];
      float vr = v.x*cw - v.y*sw;
      float vi = v.x*sw + v.y*cw;
      z[i0] = make_float2(u.x+vr, u.y+vi);
      z[i1] = make_float2(u.x-vr, u.y-vi);
    }
    __syncthreads();
  }
  float2* out = xhat + (size_t)row * NFREQ;
#pragma unroll
  for (int i = 0; i < 4; i++) {
    int k = tid + 256*i;
    float2 Zk = z[k];
    float2 Zn = z[(NCPLX - k) & (NCPLX-1)];
    float Er = 0.5f*(Zk.x + Zn.x), Ei = 0.5f*(Zk.y - Zn.y);
    float dr = 0.5f*(Zk.x - Zn.x), di = 0.5f*(Zk.y + Zn.y);
    float Or = di, Oi = -dr;                          // O = -i*(Zk-conj(Zn))/2
    float ang = -3.14159265358979323846f * (float)k / 1024.0f;
    float sw, cw; __sincosf(ang, &sw, &cw);
    out[k] = make_float2(Er + cw*Or - sw*Oi, Ei + sw*Or + cw*Oi);
  }
  if (tid == 0) {
    float2 Z0 = z[0];
    out[NCPLX] = make_float2(Z0.x - Z0.y, 0.0f);      // Nyquist
  }
}

// ---------------- causal cumsum over S (3 phases) -----------------------------
__global__ __launch_bounds__(256) void scan_partial(const float2* __restrict__ xhat,
                                                    const float* __restrict__ kvs,
                                                    float2* __restrict__ partial) {
  int bid = blockIdx.x;
  int fc = bid % FCB, sc = (bid / FCB) % NSC, b = bid / (FCB*NSC);
  int f = fc*256 + threadIdx.x;
  if (f >= NFREQ) return;
  float ks = kvs[f];
  const float2* p = xhat + ((size_t)b*SEQ + sc*SCH)*NFREQ + f;
  float sr = 0.f, si = 0.f;
#pragma unroll 8
  for (int s = 0; s < SCH; s++) {
    float2 v = p[(size_t)s*NFREQ];
    sr += v.x; si += v.y;
  }
  partial[((size_t)b*NSC + sc)*NFREQ + f] = make_float2(sr*ks, si*ks);
}

__global__ __launch_bounds__(256) void scan_offsets(float2* __restrict__ partial) {
  int fc = blockIdx.x % FCB, b = blockIdx.x / FCB;
  int f = fc*256 + threadIdx.x;
  if (f >= NFREQ) return;
  float2* p = partial + (size_t)b*NSC*NFREQ + f;
  float rr = 0.f, ri = 0.f;
#pragma unroll
  for (int sc = 0; sc < NSC; sc++) {
    float2 t = p[(size_t)sc*NFREQ];
    p[(size_t)sc*NFREQ] = make_float2(rr, ri);        // exclusive
    rr += t.x; ri += t.y;
  }
}

// in-place: xhat[b,s,f] <- qv = (Q[f]*xhat) * cumsum_{t<=s}(K[f]*xhat)
__global__ __launch_bounds__(256) void scan_apply(float2* __restrict__ xhat,
                                                  const float* __restrict__ kvs,
                                                  const float* __restrict__ qs_,
                                                  const float2* __restrict__ partial) {
  int bid = blockIdx.x;
  int fc = bid % FCB, sc = (bid / FCB) % NSC, b = bid / (FCB*NSC);
  int f = fc*256 + threadIdx.x;
  if (f >= NFREQ) return;
  float ks = kvs[f], qsc = qs_[f];
  float2 off = partial[((size_t)b*NSC + sc)*NFREQ + f];
  float rr = off.x, ri = off.y;
  float2* p = xhat + ((size_t)b*SEQ + sc*SCH)*NFREQ + f;
#pragma unroll 4
  for (int s = 0; s < SCH; s++) {
    float2 v = p[(size_t)s*NFREQ];
    rr += v.x * ks; ri += v.y * ks;                   // inclusive cumsum of kv
    float qr = qsc*(v.x*rr - v.y*ri);
    float qi = qsc*(v.x*ri + v.y*rr);
    p[(size_t)s*NFREQ] = make_float2(qr, qi);
  }
}

// ---------------- inverse rfft -> bf16 values ---------------------------------
__global__ __launch_bounds__(256) void fft_inv(const float2* __restrict__ qv,
                                               unsigned short* __restrict__ v) {
  __shared__ float2 z[NCPLX];
  const int row = blockIdx.x;
  const int tid = threadIdx.x;
  const float2* q = qv + (size_t)row * NFREQ;
#pragma unroll
  for (int i = 0; i < 4; i++) {
    int k = tid + 256*i;                               // 0..1023
    float2 Xk = q[k];
    float2 Xn = q[NCPLX - k];
    float Er = 0.5f*(Xk.x + Xn.x), Ei = 0.5f*(Xk.y - Xn.y);
    float dr = 0.5f*(Xk.x - Xn.x), di = 0.5f*(Xk.y + Xn.y);
    float ang = 3.14159265358979323846f * (float)k / 1024.0f;
    float sw, cw; __sincosf(ang, &sw, &cw);
    float Or = dr*cw - di*sw, Oi = dr*sw + di*cw;      // O = ((Xk-conj(Xn))/2)*e^{+i pi k/N}
    const float scl = 1.0f/1024.0f;
    z[bitrev10(k)] = make_float2(scl*(Er - Oi), scl*(Ei + Or)); // Z = E + iO
  }
  __syncthreads();
#pragma unroll
  for (int s = 1; s <= 10; s++) {
    const int half = 1 << (s-1);
#pragma unroll
    for (int bi = 0; bi < 2; bi++) {
      int b  = tid + 256*bi;
      int j  = b & (half-1);
      int i0 = ((b >> (s-1)) << s) + j;
      int i1 = i0 + half;
      float ang = 3.14159265358979323846f * (float)j / (float)half;  // +ve: inverse
      float sw, cw; __sincosf(ang, &sw, &cw);
      float2 u = z[i0], v2 = z[i1];
      float vr = v2.x*cw - v2.y*sw;
      float vi = v2.x*sw + v2.y*cw;
      z[i0] = make_float2(u.x+vr, u.y+vi);
      z[i1] = make_float2(u.x-vr, u.y-vi);
    }
    __syncthreads();
  }
  unsigned* vr32 = (unsigned*)(v + (size_t)row * DIM);
#pragma unroll
  for (int i = 0; i < 4; i++) {
    int n = tid + 256*i;
    float2 t = z[n];                                   // x[2n]=Re, x[2n+1]=Im
    vr32[n] = (unsigned)f2bf(t.x) | ((unsigned)f2bf(t.y) << 16);
  }
}

// ---------------- w fp32 -> bf16 ----------------------------------------------
__global__ __launch_bounds__(256) void w_to_bf16(const float* __restrict__ w,
                                                 unsigned short* __restrict__ wb) {
  size_t idx = (size_t)blockIdx.x * 256 + threadIdx.x; // 1,048,576 threads x 4 elems
  float4 v = ((const float4*)w)[idx];
  uint2 o;
  o.x = (unsigned)f2bf(v.x) | ((unsigned)f2bf(v.y) << 16);
  o.y = (unsigned)f2bf(v.z) | ((unsigned)f2bf(v.w) << 16);
  ((uint2*)wb)[idx] = o;
}

// ---------------- GEMM: C[M,N] = A[M,K] * B[N,K]^T, bf16->fp32 ----------------
#define BM 128
#define BN 128
#define BKG 64

__global__ __launch_bounds__(256) void gemm_bt(const unsigned short* __restrict__ A,
                                               const unsigned short* __restrict__ B,
                                               float* __restrict__ C) {
  __shared__ unsigned short As[BM*BKG];
  __shared__ unsigned short Bs[BN*BKG];
  const int tid  = threadIdx.x;
  const int lane = tid & 63;
  const int wave = tid >> 6;
  const int wr = wave >> 1, wc = wave & 1;
  const int nbn = DIM / BN;                            // 16
  const int bm = blockIdx.x / nbn, bn = blockIdx.x % nbn;
  const size_t m0 = (size_t)bm * BM, n0 = (size_t)bn * BN;

  f32x4 acc[4][4] = {};

  const int l15 = lane & 15;
  const int lhi = lane >> 4;

  for (int kt = 0; kt < DIM; kt += BKG) {
#pragma unroll
    for (int i = 0; i < 4; i++) {
      int ci  = i*256 + tid;                           // 16B chunk id, 0..1023
      int row = ci >> 3;
      int cc  = (ci & 7) * 8;                          // element col within BK
      __builtin_amdgcn_global_load_lds(
          (const __attribute__((address_space(1))) void*)(A + (m0+row)*DIM + kt + cc),
          (__attribute__((address_space(3))) void*)(As + (size_t)ci*8), 16, 0, 0);
      __builtin_amdgcn_global_load_lds(
          (const __attribute__((address_space(1))) void*)(B + (n0+row)*DIM + kt + cc),
          (__attribute__((address_space(3))) void*)(Bs + (size_t)ci*8), 16, 0, 0);
    }
    __syncthreads();
#pragma unroll
    for (int kk = 0; kk < 2; kk++) {
      bf16x8 af[4], bfv[4];
#pragma unroll
      for (int m = 0; m < 4; m++)
        af[m] = *(const bf16x8*)&As[(wr*64 + m*16 + l15)*BKG + kk*32 + lhi*8];
#pragma unroll
      for (int n = 0; n < 4; n++)
        bfv[n] = *(const bf16x8*)&Bs[(wc*64 + n*16 + l15)*BKG + kk*32 + lhi*8];
#pragma unroll
      for (int m = 0; m < 4; m++)
#pragma unroll
        for (int n = 0; n < 4; n++)
          acc[m][n] = __builtin_amdgcn_mfma_f32_16x16x32_bf16(af[m], bfv[n], acc[m][n], 0, 0, 0);
    }
    __syncthreads();
  }

  const int crow = lhi * 4;   // D: row = (lane>>4)*4 + j, col = lane&15
#pragma unroll
  for (int m = 0; m < 4; m++)
#pragma unroll
    for (int n = 0; n < 4; n++) {
      float* cp = C + (m0 + wr*64 + m*16 + crow) * DIM + n0 + wc*64 + n*16 + l15;
#pragma unroll
      for (int j = 0; j < 4; j++)
        cp[(size_t)j * DIM] = acc[m][n][j];
    }
}

// ---------------- launch -------------------------------------------------------
extern "C" void kernel_launch(void* const* d_in, const int* in_sizes, int n_in,
                              void* d_out, int out_size, void* d_ws, size_t ws_size,
                              hipStream_t stream) {
  const float* x    = (const float*)d_in[0];
  const float* qry  = (const float*)d_in[1];
  const float* kvs  = (const float*)d_in[2];
  const float* wout = (const float*)d_in[3];
  float* out = (float*)d_out;

  char* ws = (char*)d_ws;
  size_t off = 0;
  float2* xhat = (float2*)(ws + off);                    // qv in-place later
  off += (size_t)ROWS * NFREQ * sizeof(float2);          // 134.3 MB
  off = (off + 255) & ~(size_t)255;
  float2* partial = (float2*)(ws + off);
  off += (size_t)BATCH * NSC * NFREQ * sizeof(float2);   // 0.5 MB
  off = (off + 255) & ~(size_t)255;
  unsigned short* vbf = (unsigned short*)(ws + off);
  off += (size_t)ROWS * DIM * sizeof(unsigned short);    // 67 MB
  off = (off + 255) & ~(size_t)255;
  unsigned short* wbf = (unsigned short*)(ws + off);     // 8.4 MB

  hipLaunchKernelGGL(w_to_bf16,   dim3((DIM*DIM)/(256*4)), dim3(256), 0, stream, wout, wbf);
  hipLaunchKernelGGL(fft_fwd,     dim3(ROWS),              dim3(256), 0, stream, x, xhat);
  hipLaunchKernelGGL(scan_partial,dim3(BATCH*NSC*FCB),     dim3(256), 0, stream, xhat, kvs, partial);
  hipLaunchKernelGGL(scan_offsets,dim3(BATCH*FCB),         dim3(256), 0, stream, partial);
  hipLaunchKernelGGL(scan_apply,  dim3(BATCH*NSC*FCB),     dim3(256), 0, stream, xhat, kvs, qry, partial);
  hipLaunchKernelGGL(fft_inv,     dim3(ROWS),              dim3(256), 0, stream, xhat, vbf);
  hipLaunchKernelGGL(gemm_bt,     dim3((ROWS/BM)*(DIM/BN)),dim3(256), 0, stream, vbf, wbf, out);
}

// Round 2
// 381.608 us; speedup vs baseline: 1.2321x; 1.2321x over previous
//
#include <hip/hip_runtime.h>
#include <hip/hip_bf16.h>
#include <stdint.h>

#define BATCH 4
#define SEQ   4096
#define DIM   2048
#define NFREQ 1025
#define NCPLX 1024
#define ROWS  (BATCH*SEQ)   // 16384

// scan decomposition
#define SCH 256            // s-chunk length
#define NSC (SEQ/SCH)      // 16 chunks
#define FCB 5              // ceil(1025/256) freq-column blocks

typedef __bf16 bf16x8 __attribute__((ext_vector_type(8)));
typedef float  f32x4  __attribute__((ext_vector_type(4)));

__device__ __forceinline__ unsigned bitrev10(unsigned x) { return __brev(x) >> 22; }

__device__ __forceinline__ unsigned short f2bf(float f) {
  union { float f; unsigned u; } v; v.f = f;
  unsigned r = v.u + 0x7fffu + ((v.u >> 16) & 1u);
  return (unsigned short)(r >> 16);
}

// ---------------- forward rfft (packed-real, 1024-pt complex DIT) -------------
__global__ __launch_bounds__(256) void fft_fwd(const float* __restrict__ x,
                                               float2* __restrict__ xhat) {
  __shared__ float2 z[NCPLX];
  const int row = blockIdx.x;
  const int tid = threadIdx.x;
  const float* xr = x + (size_t)row * DIM;
#pragma unroll
  for (int i = 0; i < 4; i++) {
    int n = tid + 256*i;
    float2 v = *(const float2*)(xr + 2*n);   // z[n] = x[2n] + i x[2n+1]
    z[bitrev10(n)] = v;
  }
  __syncthreads();
#pragma unroll
  for (int s = 1; s <= 10; s++) {
    const int half = 1 << (s-1);
#pragma unroll
    for (int bi = 0; bi < 2; bi++) {
      int b  = tid + 256*bi;                 // butterfly 0..511
      int j  = b & (half-1);
      int i0 = ((b >> (s-1)) << s) + j;
      int i1 = i0 + half;
      float ang = -3.14159265358979323846f * (float)j / (float)half;
      float sw, cw; __sincosf(ang, &sw, &cw);
      float2 u = z[i0], v = z[i1];
      float vr = v.x*cw - v.y*sw;
      float vi = v.x*sw + v.y*cw;
      z[i0] = make_float2(u.x+vr, u.y+vi);
      z[i1] = make_float2(u.x-vr, u.y-vi);
    }
    __syncthreads();
  }
  float2* out = xhat + (size_t)row * NFREQ;
#pragma unroll
  for (int i = 0; i < 4; i++) {
    int k = tid + 256*i;
    float2 Zk = z[k];
    float2 Zn = z[(NCPLX - k) & (NCPLX-1)];
    float Er = 0.5f*(Zk.x + Zn.x), Ei = 0.5f*(Zk.y - Zn.y);
    float dr = 0.5f*(Zk.x - Zn.x), di = 0.5f*(Zk.y + Zn.y);
    float Or = di, Oi = -dr;                          // O = -i*(Zk-conj(Zn))/2
    float ang = -3.14159265358979323846f * (float)k / 1024.0f;
    float sw, cw; __sincosf(ang, &sw, &cw);
    out[k] = make_float2(Er + cw*Or - sw*Oi, Ei + sw*Or + cw*Oi);
  }
  if (tid == 0) {
    float2 Z0 = z[0];
    out[NCPLX] = make_float2(Z0.x - Z0.y, 0.0f);      // Nyquist
  }
}

// ---------------- causal cumsum over S (3 phases) -----------------------------
__global__ __launch_bounds__(256) void scan_partial(const float2* __restrict__ xhat,
                                                    const float* __restrict__ kvs,
                                                    float2* __restrict__ partial) {
  int bid = blockIdx.x;
  int fc = bid % FCB, sc = (bid / FCB) % NSC, b = bid / (FCB*NSC);
  int f = fc*256 + threadIdx.x;
  if (f >= NFREQ) return;
  float ks = kvs[f];
  const float2* p = xhat + ((size_t)b*SEQ + sc*SCH)*NFREQ + f;
  float sr = 0.f, si = 0.f;
#pragma unroll 8
  for (int s = 0; s < SCH; s++) {
    float2 v = p[(size_t)s*NFREQ];
    sr += v.x; si += v.y;
  }
  partial[((size_t)b*NSC + sc)*NFREQ + f] = make_float2(sr*ks, si*ks);
}

__global__ __launch_bounds__(256) void scan_offsets(float2* __restrict__ partial) {
  int fc = blockIdx.x % FCB, b = blockIdx.x / FCB;
  int f = fc*256 + threadIdx.x;
  if (f >= NFREQ) return;
  float2* p = partial + (size_t)b*NSC*NFREQ + f;
  float rr = 0.f, ri = 0.f;
#pragma unroll
  for (int sc = 0; sc < NSC; sc++) {
    float2 t = p[(size_t)sc*NFREQ];
    p[(size_t)sc*NFREQ] = make_float2(rr, ri);        // exclusive
    rr += t.x; ri += t.y;
  }
}

// in-place: xhat[b,s,f] <- qv = (Q[f]*xhat) * cumsum_{t<=s}(K[f]*xhat)
__global__ __launch_bounds__(256) void scan_apply(float2* __restrict__ xhat,
                                                  const float* __restrict__ kvs,
                                                  const float* __restrict__ qs_,
                                                  const float2* __restrict__ partial) {
  int bid = blockIdx.x;
  int fc = bid % FCB, sc = (bid / FCB) % NSC, b = bid / (FCB*NSC);
  int f = fc*256 + threadIdx.x;
  if (f >= NFREQ) return;
  float ks = kvs[f], qsc = qs_[f];
  float2 off = partial[((size_t)b*NSC + sc)*NFREQ + f];
  float rr = off.x, ri = off.y;
  float2* p = xhat + ((size_t)b*SEQ + sc*SCH)*NFREQ + f;
#pragma unroll 4
  for (int s = 0; s < SCH; s++) {
    float2 v = p[(size_t)s*NFREQ];
    rr += v.x * ks; ri += v.y * ks;                   // inclusive cumsum of kv
    float qr = qsc*(v.x*rr - v.y*ri);
    float qi = qsc*(v.x*ri + v.y*rr);
    p[(size_t)s*NFREQ] = make_float2(qr, qi);
  }
}

// ---------------- inverse rfft -> bf16 values ---------------------------------
__global__ __launch_bounds__(256) void fft_inv(const float2* __restrict__ qv,
                                               unsigned short* __restrict__ v) {
  __shared__ float2 z[NCPLX];
  const int row = blockIdx.x;
  const int tid = threadIdx.x;
  const float2* q = qv + (size_t)row * NFREQ;
#pragma unroll
  for (int i = 0; i < 4; i++) {
    int k = tid + 256*i;                               // 0..1023
    float2 Xk = q[k];
    float2 Xn = q[NCPLX - k];
    float Er = 0.5f*(Xk.x + Xn.x), Ei = 0.5f*(Xk.y - Xn.y);
    float dr = 0.5f*(Xk.x - Xn.x), di = 0.5f*(Xk.y + Xn.y);
    float ang = 3.14159265358979323846f * (float)k / 1024.0f;
    float sw, cw; __sincosf(ang, &sw, &cw);
    float Or = dr*cw - di*sw, Oi = dr*sw + di*cw;      // O = ((Xk-conj(Xn))/2)*e^{+i pi k/N}
    const float scl = 1.0f/1024.0f;
    z[bitrev10(k)] = make_float2(scl*(Er - Oi), scl*(Ei + Or)); // Z = E + iO
  }
  __syncthreads();
#pragma unroll
  for (int s = 1; s <= 10; s++) {
    const int half = 1 << (s-1);
#pragma unroll
    for (int bi = 0; bi < 2; bi++) {
      int b  = tid + 256*bi;
      int j  = b & (half-1);
      int i0 = ((b >> (s-1)) << s) + j;
      int i1 = i0 + half;
      float ang = 3.14159265358979323846f * (float)j / (float)half;  // +ve: inverse
      float sw, cw; __sincosf(ang, &sw, &cw);
      float2 u = z[i0], v2 = z[i1];
      float vr = v2.x*cw - v2.y*sw;
      float vi = v2.x*sw + v2.y*cw;
      z[i0] = make_float2(u.x+vr, u.y+vi);
      z[i1] = make_float2(u.x-vr, u.y-vi);
    }
    __syncthreads();
  }
  unsigned* vr32 = (unsigned*)(v + (size_t)row * DIM);
#pragma unroll
  for (int i = 0; i < 4; i++) {
    int n = tid + 256*i;
    float2 t = z[n];                                   // x[2n]=Re, x[2n+1]=Im
    vr32[n] = (unsigned)f2bf(t.x) | ((unsigned)f2bf(t.y) << 16);
  }
}

// ---------------- w fp32 -> bf16 ----------------------------------------------
__global__ __launch_bounds__(256) void w_to_bf16(const float* __restrict__ w,
                                                 unsigned short* __restrict__ wb) {
  size_t idx = (size_t)blockIdx.x * 256 + threadIdx.x; // 1,048,576 threads x 4 elems
  float4 v = ((const float4*)w)[idx];
  uint2 o;
  o.x = (unsigned)f2bf(v.x) | ((unsigned)f2bf(v.y) << 16);
  o.y = (unsigned)f2bf(v.z) | ((unsigned)f2bf(v.w) << 16);
  ((uint2*)wb)[idx] = o;
}

// ============ 256x256 8-phase GEMM: C[M,N] = A[M,K] * B[N,K]^T, bf16->fp32 =====
// 512 threads = 8 waves (2 M x 4 N). Per wave: 64x32 piece of each 128x128
// C-quadrant (mh,nh). K-step 64, double-buffered LDS (128 KiB), XOR-swizzled.
// Counted vmcnt(8) at phases 4/8 only; stages land in just-freed half-slots.

#define NKT (DIM/64)      // 32 K-tiles
#define NIT (NKT/2)       // 16 iterations of 2 K-tiles

#define BARX() do{ __builtin_amdgcn_s_barrier(); __builtin_amdgcn_sched_barrier(0); }while(0)
#define VMW(N) do{ asm volatile("s_waitcnt vmcnt(" #N ")" ::: "memory"); __builtin_amdgcn_sched_barrier(0); }while(0)

// A-frag load: half MH of buffer B_, 8 reads (m=0..3, kk=0..1)
#define LOADA(B_, MH) do{ _Pragma("unroll") for (int m_=0;m_<4;++m_) _Pragma("unroll") for (int kk_=0;kk_<2;++kk_){ \
    int rA_ = wm*64 + m_*16 + l15; \
    aF[m_][kk_] = *(const bf16x8*)(smem + ((B_)*2+(MH))*16384 + rA_*128 + ((kk_*64 + lhi*16) ^ ((rA_&7)<<4))); } }while(0)

// B-frag load into DST: half NH of buffer B_, 4 reads (n=0..1, kk=0..1)
#define LOADB(DST, B_, NH) do{ _Pragma("unroll") for (int n_=0;n_<2;++n_) _Pragma("unroll") for (int kk_=0;kk_<2;++kk_){ \
    int rB_ = wn*32 + n_*16 + l15; \
    DST[n_][kk_] = *(const bf16x8*)(smem + 65536 + ((B_)*2+(NH))*16384 + rB_*128 + ((kk_*64 + lhi*16) ^ ((rB_&7)<<4))); } }while(0)

// 16 MFMA for quadrant (MH,NH) using current aF and B-frag set BF
#define MM(MH, NH, BF) do{ __builtin_amdgcn_s_setprio(1); \
    _Pragma("unroll") for (int kk_=0;kk_<2;++kk_) _Pragma("unroll") for (int m_=0;m_<4;++m_) _Pragma("unroll") for (int n_=0;n_<2;++n_) \
      acc[MH][NH][m_][n_] = __builtin_amdgcn_mfma_f32_16x16x32_bf16(aF[m_][kk_], BF[n_][kk_], acc[MH][NH][m_][n_], 0, 0, 0); \
    __builtin_amdgcn_s_setprio(0); }while(0)

// stage one 128x64 half-tile: REG=0 (A) or 65536 (B); linear LDS dest,
// inverse-swizzled global source slot (sl ^ (r&7)) -- both-sides swizzle.
#define STAGEH(REG, B_, H_, GP, ROW0, KT) do{ _Pragma("unroll") for (int c_=0;c_<2;++c_){ \
    int ci_ = c_*512 + tid; int r_ = ci_>>3, sl_ = ci_&7; \
    const unsigned short* sp_ = (GP) + (size_t)((ROW0) + (H_)*128 + r_)*DIM + (KT) + ((sl_ ^ (r_&7))*8); \
    __builtin_amdgcn_global_load_lds((const __attribute__((address_space(1))) void*)sp_, \
      (__attribute__((address_space(3))) void*)(smem + (REG) + ((B_)*2+(H_))*16384 + ci_*16), 16, 0, 0); } }while(0)

__global__ __launch_bounds__(512, 2) void gemm256(const unsigned short* __restrict__ A,
                                                  const unsigned short* __restrict__ B,
                                                  float* __restrict__ C) {
  __shared__ __align__(16) char smem[131072];   // A: 2buf x 2half x 128x64 bf16 = 64KB; B same
  const int tid = threadIdx.x;
  const int lane = tid & 63;
  const int wid  = tid >> 6;
  const int wm = wid >> 2, wn = wid & 3;        // 2 x 4 wave grid
  const int l15 = lane & 15, lhi = lane >> 4;

  // bn = bid&7 doubles as XCD swizzle: each XCD keeps one B-panel L2-resident
  const int bn = blockIdx.x & 7, bm = blockIdx.x >> 3;
  const int m0 = bm * 256, n0 = bn * 256;

  f32x4 acc[2][2][4][2] = {};
  bf16x8 aF[4][2], bF0[2][2], bF1[2][2];

  // prologue: stage K-tiles 0 (buf0) and 1 (buf1); wait tile0, keep tile1 in flight
  STAGEH(0,     0,0, A, m0, 0);  STAGEH(65536, 0,0, B, n0, 0);
  STAGEH(65536, 0,1, B, n0, 0);  STAGEH(0,     0,1, A, m0, 0);
  STAGEH(0,     1,0, A, m0, 64); STAGEH(65536, 1,0, B, n0, 64);
  STAGEH(65536, 1,1, B, n0, 64); STAGEH(0,     1,1, A, m0, 64);
  VMW(8);
  BARX();

#pragma unroll 1
  for (int j = 0; j < NIT-1; ++j) {
    const int kA = (2*j+2)*64, kB = (2*j+3)*64;
    // ---- K-tile 2j (buf0) ----
    LOADA(0,0); LOADB(bF0, 0,0);                       // p1 (0,0)
    BARX(); MM(0,0,bF0); BARX();
    LOADB(bF1, 0,1);                                   // p2 (0,1)
    STAGEH(0, 0,0, A, m0, kA); STAGEH(65536, 0,0, B, n0, kA);
    BARX(); MM(0,1,bF1); BARX();
    LOADA(0,1);                                        // p3 (1,0)
    STAGEH(65536, 0,1, B, n0, kA);
    BARX(); MM(1,0,bF0); BARX();
    STAGEH(0, 0,1, A, m0, kA);                         // p4 (1,1)
    VMW(8);
    BARX(); MM(1,1,bF1); BARX();
    // ---- K-tile 2j+1 (buf1) ----
    LOADA(1,0); LOADB(bF0, 1,0);                       // p5 (0,0)
    BARX(); MM(0,0,bF0); BARX();
    LOADB(bF1, 1,1);                                   // p6 (0,1)
    STAGEH(0, 1,0, A, m0, kB); STAGEH(65536, 1,0, B, n0, kB);
    BARX(); MM(0,1,bF1); BARX();
    LOADA(1,1);                                        // p7 (1,0)
    STAGEH(65536, 1,1, B, n0, kB);
    BARX(); MM(1,0,bF0); BARX();
    STAGEH(0, 1,1, A, m0, kB);                         // p8 (1,1)
    VMW(8);
    BARX(); MM(1,1,bF1); BARX();
  }
  // ---- peeled final iteration (K-tiles 30,31): no stages ----
  LOADA(0,0); LOADB(bF0, 0,0);
  BARX(); MM(0,0,bF0); BARX();
  LOADB(bF1, 0,1);
  BARX(); MM(0,1,bF1); BARX();
  LOADA(0,1);
  BARX(); MM(1,0,bF0); BARX();
  VMW(0);                                              // tile31 fully resident
  BARX(); MM(1,1,bF1); BARX();
  LOADA(1,0); LOADB(bF0, 1,0);
  BARX(); MM(0,0,bF0); BARX();
  LOADB(bF1, 1,1);
  BARX(); MM(0,1,bF1); BARX();
  LOADA(1,1);
  BARX(); MM(1,0,bF0); BARX();
  BARX(); MM(1,1,bF1); BARX();

  // epilogue: C write (D layout: row = (lane>>4)*4 + j, col = lane&15)
  const int crow = lhi * 4;
#pragma unroll
  for (int mh = 0; mh < 2; ++mh)
#pragma unroll
    for (int nh = 0; nh < 2; ++nh)
#pragma unroll
      for (int m_ = 0; m_ < 4; ++m_)
#pragma unroll
        for (int n_ = 0; n_ < 2; ++n_) {
          float* cp = C + (size_t)(m0 + mh*128 + wm*64 + m_*16 + crow) * DIM
                        + (n0 + nh*128 + wn*32 + n_*16 + l15);
#pragma unroll
          for (int j2 = 0; j2 < 4; ++j2)
            cp[(size_t)j2 * DIM] = acc[mh][nh][m_][n_][j2];
        }
}

// ---------------- launch -------------------------------------------------------
extern "C" void kernel_launch(void* const* d_in, const int* in_sizes, int n_in,
                              void* d_out, int out_size, void* d_ws, size_t ws_size,
                              hipStream_t stream) {
  const float* x    = (const float*)d_in[0];
  const float* qry  = (const float*)d_in[1];
  const float* kvs  = (const float*)d_in[2];
  const float* wout = (const float*)d_in[3];
  float* out = (float*)d_out;

  char* ws = (char*)d_ws;
  size_t off = 0;
  float2* xhat = (float2*)(ws + off);                    // qv in-place later
  off += (size_t)ROWS * NFREQ * sizeof(float2);          // 134.3 MB
  off = (off + 255) & ~(size_t)255;
  float2* partial = (float2*)(ws + off);
  off += (size_t)BATCH * NSC * NFREQ * sizeof(float2);   // 0.5 MB
  off = (off + 255) & ~(size_t)255;
  unsigned short* vbf = (unsigned short*)(ws + off);
  off += (size_t)ROWS * DIM * sizeof(unsigned short);    // 67 MB
  off = (off + 255) & ~(size_t)255;
  unsigned short* wbf = (unsigned short*)(ws + off);     // 8.4 MB

  hipLaunchKernelGGL(w_to_bf16,   dim3((DIM*DIM)/(256*4)), dim3(256), 0, stream, wout, wbf);
  hipLaunchKernelGGL(fft_fwd,     dim3(ROWS),              dim3(256), 0, stream, x, xhat);
  hipLaunchKernelGGL(scan_partial,dim3(BATCH*NSC*FCB),     dim3(256), 0, stream, xhat, kvs, partial);
  hipLaunchKernelGGL(scan_offsets,dim3(BATCH*FCB),         dim3(256), 0, stream, partial);
  hipLaunchKernelGGL(scan_apply,  dim3(BATCH*NSC*FCB),     dim3(256), 0, stream, xhat, kvs, qry, partial);
  hipLaunchKernelGGL(fft_inv,     dim3(ROWS),              dim3(256), 0, stream, xhat, vbf);
  hipLaunchKernelGGL(gemm256,     dim3((ROWS/256)*(DIM/256)), dim3(512), 0, stream, vbf, wbf, out);
}

// Round 3
// 317.130 us; speedup vs baseline: 1.4826x; 1.2033x over previous
//
#include <hip/hip_runtime.h>
#include <hip/hip_bf16.h>
#include <stdint.h>

#define BATCH 4
#define SEQ   4096
#define DIM   2048
#define NFREQ 1025
#define NCPLX 1024
#define ROWS  (BATCH*SEQ)   // 16384
#define NFP   1026          // padded xhat row stride (float2), 16B-aligned rows

// scan decomposition
#define SCH 64             // s-chunk length
#define NSC (SEQ/SCH)      // 64 chunks
#define PFB 3              // pair-column blocks: 3*256 >= 513 freq-pairs

typedef __bf16 bf16x8 __attribute__((ext_vector_type(8)));
typedef float  f32x4  __attribute__((ext_vector_type(4)));

__device__ __forceinline__ int drev4(int n) {  // reverse 5 base-4 digits of 10-bit n
  return ((n&3)<<8) | (((n>>2)&3)<<6) | (((n>>4)&3)<<4) | (((n>>6)&3)<<2) | ((n>>8)&3);
}
#define ZI(i) ((i) + ((i)>>4))   // LDS pad: every 16 float2 -> +1 (caps conflicts ~4-way)

__device__ __forceinline__ float2 cmulf(float2 a, float2 b) {
  return make_float2(a.x*b.x - a.y*b.y, a.x*b.y + a.y*b.x);
}

__device__ __forceinline__ unsigned short f2bf(float f) {
  union { float f; unsigned u; } v; v.f = f;
  unsigned r = v.u + 0x7fffu + ((v.u >> 16) & 1u);
  return (unsigned short)(r >> 16);
}

// ---------------- radix-4 1024-pt in-place DIT (digit-reversed input) ---------
template<int INV>
__device__ __forceinline__ void fft_stages(float2* z, int tid) {
  { // stage q=1 (no twiddles)
    int b4 = tid*4;
    float2 x0=z[ZI(b4)], x1=z[ZI(b4+1)], x2=z[ZI(b4+2)], x3=z[ZI(b4+3)];
    float2 a = make_float2(x0.x+x2.x, x0.y+x2.y), b = make_float2(x0.x-x2.x, x0.y-x2.y);
    float2 c = make_float2(x1.x+x3.x, x1.y+x3.y), d = make_float2(x1.x-x3.x, x1.y-x3.y);
    z[ZI(b4)]   = make_float2(a.x+c.x, a.y+c.y);
    z[ZI(b4+2)] = make_float2(a.x-c.x, a.y-c.y);
    if (!INV) { z[ZI(b4+1)] = make_float2(b.x+d.y, b.y-d.x);
                z[ZI(b4+3)] = make_float2(b.x-d.y, b.y+d.x); }
    else      { z[ZI(b4+1)] = make_float2(b.x-d.y, b.y+d.x);
                z[ZI(b4+3)] = make_float2(b.x+d.y, b.y-d.x); }
  }
  __syncthreads();
#pragma unroll
  for (int s = 0; s < 4; ++s) {
    const int lq = 2 + 2*s;          // q = 4,16,64,256
    const int q  = 1 << lq;
    int j = tid & (q-1), g = tid >> lq;
    int base = (g << (lq+2)) + j;
    float ang = (INV ? 6.2831853071795864769f : -6.2831853071795864769f)
                * (float)j / (float)(4*q);
    float sw, cw; __sincosf(ang, &sw, &cw);
    float2 w1 = make_float2(cw, sw);
    float2 w2 = cmulf(w1, w1), w3 = cmulf(w2, w1);
    float2 x0 = z[ZI(base)];
    float2 x1 = cmulf(z[ZI(base+q)],   w1);
    float2 x2 = cmulf(z[ZI(base+2*q)], w2);
    float2 x3 = cmulf(z[ZI(base+3*q)], w3);
    float2 a = make_float2(x0.x+x2.x, x0.y+x2.y), b = make_float2(x0.x-x2.x, x0.y-x2.y);
    float2 c = make_float2(x1.x+x3.x, x1.y+x3.y), d = make_float2(x1.x-x3.x, x1.y-x3.y);
    z[ZI(base)]     = make_float2(a.x+c.x, a.y+c.y);
    z[ZI(base+2*q)] = make_float2(a.x-c.x, a.y-c.y);
    if (!INV) { z[ZI(base+q)]   = make_float2(b.x+d.y, b.y-d.x);
                z[ZI(base+3*q)] = make_float2(b.x-d.y, b.y+d.x); }
    else      { z[ZI(base+q)]   = make_float2(b.x-d.y, b.y+d.x);
                z[ZI(base+3*q)] = make_float2(b.x+d.y, b.y-d.x); }
    __syncthreads();
  }
}

// ---------------- forward rfft (packed-real) ----------------------------------
__global__ __launch_bounds__(256) void fft_fwd(const float* __restrict__ x,
                                               float2* __restrict__ xhat) {
  __shared__ float2 z[ZI(1023)+2];
  const int row = blockIdx.x;
  const int tid = threadIdx.x;
  const float* xr = x + (size_t)row * DIM;
#pragma unroll
  for (int i = 0; i < 2; i++) {
    float4 v = ((const float4*)xr)[tid + 256*i];       // z[2t], z[2t+1]
    int n0 = 2*(tid + 256*i);
    z[ZI(drev4(n0))]   = make_float2(v.x, v.y);
    z[ZI(drev4(n0+1))] = make_float2(v.z, v.w);
  }
  __syncthreads();
  fft_stages<0>(z, tid);
  float2* out = xhat + (size_t)row * NFP;
#pragma unroll
  for (int i = 0; i < 4; i++) {
    int k = tid + 256*i;
    float2 Zk = z[ZI(k)];
    float2 Zn = z[ZI((NCPLX - k) & (NCPLX-1))];
    float Er = 0.5f*(Zk.x + Zn.x), Ei = 0.5f*(Zk.y - Zn.y);
    float dr = 0.5f*(Zk.x - Zn.x), di = 0.5f*(Zk.y + Zn.y);
    float Or = di, Oi = -dr;                           // O = -i*(Zk-conj(Zn))/2
    float ang = -3.14159265358979323846f * (float)k / 1024.0f;
    float sw, cw; __sincosf(ang, &sw, &cw);
    out[k] = make_float2(Er + cw*Or - sw*Oi, Ei + sw*Or + cw*Oi);
  }
  if (tid == 0) {
    float2 Z0 = z[ZI(0)];
    out[NCPLX]   = make_float2(Z0.x - Z0.y, 0.0f);     // Nyquist
    out[NCPLX+1] = make_float2(0.0f, 0.0f);            // pad
  }
}

// ---------------- causal cumsum over S (3 phases, float4 pair-columns) --------
__global__ __launch_bounds__(256) void scan_partial(const float2* __restrict__ xhat,
                                                    const float* __restrict__ kvs,
                                                    float2* __restrict__ partial) {
  int bid = blockIdx.x;
  int fc = bid % PFB, sc = (bid / PFB) % NSC, b = bid / (PFB*NSC);
  int fp = fc*256 + threadIdx.x;
  if (fp > 512) return;
  int f0 = 2*fp;
  float2 ks = (fp < 512) ? *(const float2*)(kvs + f0) : make_float2(kvs[1024], 0.f);
  const float2* rowp = xhat + ((size_t)b*SEQ + sc*SCH) * NFP + f0;
  float s0r=0.f, s0i=0.f, s1r=0.f, s1i=0.f;
#pragma unroll 8
  for (int s = 0; s < SCH; s++) {
    float4 v = *(const float4*)(rowp + (size_t)s*NFP);
    s0r += v.x; s0i += v.y; s1r += v.z; s1i += v.w;
  }
  float4 o = make_float4(s0r*ks.x, s0i*ks.x, s1r*ks.y, s1i*ks.y);
  *(float4*)(partial + ((size_t)b*NSC + sc)*NFP + f0) = o;
}

__global__ __launch_bounds__(256) void scan_offsets(float2* __restrict__ partial) {
  int fc = blockIdx.x % PFB, b = blockIdx.x / PFB;
  int fp = fc*256 + threadIdx.x;
  if (fp > 512) return;
  int f0 = 2*fp;
  float2* p = partial + (size_t)b*NSC*NFP + f0;
  float r0=0.f, i0=0.f, r1=0.f, i1=0.f;
#pragma unroll 8
  for (int sc = 0; sc < NSC; sc++) {
    float4 t = *(const float4*)(p + (size_t)sc*NFP);
    *(float4*)(p + (size_t)sc*NFP) = make_float4(r0, i0, r1, i1);  // exclusive
    r0 += t.x; i0 += t.y; r1 += t.z; i1 += t.w;
  }
}

__global__ __launch_bounds__(256) void scan_apply(float2* __restrict__ xhat,
                                                  const float* __restrict__ kvs,
                                                  const float* __restrict__ qs_,
                                                  const float2* __restrict__ partial) {
  int bid = blockIdx.x;
  int fc = bid % PFB, sc = (bid / PFB) % NSC, b = bid / (PFB*NSC);
  int fp = fc*256 + threadIdx.x;
  if (fp > 512) return;
  int f0 = 2*fp;
  float2 ks = (fp < 512) ? *(const float2*)(kvs + f0) : make_float2(kvs[1024], 0.f);
  float2 qs = (fp < 512) ? *(const float2*)(qs_ + f0) : make_float2(qs_[1024], 0.f);
  float4 off = *(const float4*)(partial + ((size_t)b*NSC + sc)*NFP + f0);
  float r0 = off.x, i0 = off.y, r1 = off.z, i1 = off.w;
  float2* rowp = xhat + ((size_t)b*SEQ + sc*SCH) * NFP + f0;
#pragma unroll 4
  for (int s = 0; s < SCH; s++) {
    float4 v = *(const float4*)(rowp + (size_t)s*NFP);
    r0 += v.x * ks.x; i0 += v.y * ks.x;
    r1 += v.z * ks.y; i1 += v.w * ks.y;
    float4 o;
    o.x = qs.x*(v.x*r0 - v.y*i0);
    o.y = qs.x*(v.x*i0 + v.y*r0);
    o.z = qs.y*(v.z*r1 - v.w*i1);
    o.w = qs.y*(v.z*i1 + v.w*r1);
    *(float4*)(rowp + (size_t)s*NFP) = o;
  }
}

// ---------------- inverse rfft -> bf16 values ---------------------------------
__global__ __launch_bounds__(256) void fft_inv(const float2* __restrict__ qv,
                                               unsigned short* __restrict__ v) {
  __shared__ float2 z[ZI(1023)+2];
  const int row = blockIdx.x;
  const int tid = threadIdx.x;
  const float2* q = qv + (size_t)row * NFP;
#pragma unroll
  for (int i = 0; i < 4; i++) {
    int k = tid + 256*i;
    float2 Xk = q[k];
    float2 Xn = q[NCPLX - k];
    float Er = 0.5f*(Xk.x + Xn.x), Ei = 0.5f*(Xk.y - Xn.y);
    float dr = 0.5f*(Xk.x - Xn.x), di = 0.5f*(Xk.y + Xn.y);
    float ang = 3.14159265358979323846f * (float)k / 1024.0f;
    float sw, cw; __sincosf(ang, &sw, &cw);
    float Or = dr*cw - di*sw, Oi = dr*sw + di*cw;
    const float scl = 1.0f/1024.0f;
    z[ZI(drev4(k))] = make_float2(scl*(Er - Oi), scl*(Ei + Or));
  }
  __syncthreads();
  fft_stages<1>(z, tid);
  unsigned* vr32 = (unsigned*)(v + (size_t)row * DIM);
#pragma unroll
  for (int i = 0; i < 4; i++) {
    int n = tid + 256*i;
    float2 t = z[ZI(n)];
    vr32[n] = (unsigned)f2bf(t.x) | ((unsigned)f2bf(t.y) << 16);
  }
}

// ---------------- w fp32 -> bf16 ----------------------------------------------
__global__ __launch_bounds__(256) void w_to_bf16(const float* __restrict__ w,
                                                 unsigned short* __restrict__ wb) {
  size_t idx = (size_t)blockIdx.x * 256 + threadIdx.x;
  float4 v = ((const float4*)w)[idx];
  uint2 o;
  o.x = (unsigned)f2bf(v.x) | ((unsigned)f2bf(v.y) << 16);
  o.y = (unsigned)f2bf(v.z) | ((unsigned)f2bf(v.w) << 16);
  ((uint2*)wb)[idx] = o;
}

// ============ 256x256 8-phase GEMM: C[M,N] = A[M,K] * B[N,K]^T, bf16->fp32 =====
#define NKT (DIM/64)      // 32 K-tiles
#define NIT (NKT/2)       // 16 iterations of 2 K-tiles

#define BARX() do{ __builtin_amdgcn_s_barrier(); __builtin_amdgcn_sched_barrier(0); }while(0)
#define VMW(N) do{ asm volatile("s_waitcnt vmcnt(" #N ")" ::: "memory"); __builtin_amdgcn_sched_barrier(0); }while(0)

#define LOADA(B_, MH) do{ _Pragma("unroll") for (int m_=0;m_<4;++m_) _Pragma("unroll") for (int kk_=0;kk_<2;++kk_){ \
    int rA_ = wm*64 + m_*16 + l15; \
    aF[m_][kk_] = *(const bf16x8*)(smem + ((B_)*2+(MH))*16384 + rA_*128 + ((kk_*64 + lhi*16) ^ ((rA_&7)<<4))); } }while(0)

#define LOADB(DST, B_, NH) do{ _Pragma("unroll") for (int n_=0;n_<2;++n_) _Pragma("unroll") for (int kk_=0;kk_<2;++kk_){ \
    int rB_ = wn*32 + n_*16 + l15; \
    DST[n_][kk_] = *(const bf16x8*)(smem + 65536 + ((B_)*2+(NH))*16384 + rB_*128 + ((kk_*64 + lhi*16) ^ ((rB_&7)<<4))); } }while(0)

#define MM(MH, NH, BF) do{ __builtin_amdgcn_s_setprio(1); \
    _Pragma("unroll") for (int kk_=0;kk_<2;++kk_) _Pragma("unroll") for (int m_=0;m_<4;++m_) _Pragma("unroll") for (int n_=0;n_<2;++n_) \
      acc[MH][NH][m_][n_] = __builtin_amdgcn_mfma_f32_16x16x32_bf16(aF[m_][kk_], BF[n_][kk_], acc[MH][NH][m_][n_], 0, 0, 0); \
    __builtin_amdgcn_s_setprio(0); }while(0)

#define STAGEH(REG, B_, H_, GP, ROW0, KT) do{ _Pragma("unroll") for (int c_=0;c_<2;++c_){ \
    int ci_ = c_*512 + tid; int r_ = ci_>>3, sl_ = ci_&7; \
    const unsigned short* sp_ = (GP) + (size_t)((ROW0) + (H_)*128 + r_)*DIM + (KT) + ((sl_ ^ (r_&7))*8); \
    __builtin_amdgcn_global_load_lds((const __attribute__((address_space(1))) void*)sp_, \
      (__attribute__((address_space(3))) void*)(smem + (REG) + ((B_)*2+(H_))*16384 + ci_*16), 16, 0, 0); } }while(0)

__global__ __launch_bounds__(512, 2) void gemm256(const unsigned short* __restrict__ A,
                                                  const unsigned short* __restrict__ B,
                                                  float* __restrict__ C) {
  __shared__ __align__(16) char smem[131072];
  const int tid = threadIdx.x;
  const int lane = tid & 63;
  const int wid  = tid >> 6;
  const int wm = wid >> 2, wn = wid & 3;
  const int l15 = lane & 15, lhi = lane >> 4;

  const int bn = blockIdx.x & 7, bm = blockIdx.x >> 3;
  const int m0 = bm * 256, n0 = bn * 256;

  f32x4 acc[2][2][4][2] = {};
  bf16x8 aF[4][2], bF0[2][2], bF1[2][2];

  STAGEH(0,     0,0, A, m0, 0);  STAGEH(65536, 0,0, B, n0, 0);
  STAGEH(65536, 0,1, B, n0, 0);  STAGEH(0,     0,1, A, m0, 0);
  STAGEH(0,     1,0, A, m0, 64); STAGEH(65536, 1,0, B, n0, 64);
  STAGEH(65536, 1,1, B, n0, 64); STAGEH(0,     1,1, A, m0, 64);
  VMW(8);
  BARX();

#pragma unroll 1
  for (int j = 0; j < NIT-1; ++j) {
    const int kA = (2*j+2)*64, kB = (2*j+3)*64;
    LOADA(0,0); LOADB(bF0, 0,0);
    BARX(); MM(0,0,bF0); BARX();
    LOADB(bF1, 0,1);
    STAGEH(0, 0,0, A, m0, kA); STAGEH(65536, 0,0, B, n0, kA);
    BARX(); MM(0,1,bF1); BARX();
    LOADA(0,1);
    STAGEH(65536, 0,1, B, n0, kA);
    BARX(); MM(1,0,bF0); BARX();
    STAGEH(0, 0,1, A, m0, kA);
    VMW(8);
    BARX(); MM(1,1,bF1); BARX();
    LOADA(1,0); LOADB(bF0, 1,0);
    BARX(); MM(0,0,bF0); BARX();
    LOADB(bF1, 1,1);
    STAGEH(0, 1,0, A, m0, kB); STAGEH(65536, 1,0, B, n0, kB);
    BARX(); MM(0,1,bF1); BARX();
    LOADA(1,1);
    STAGEH(65536, 1,1, B, n0, kB);
    BARX(); MM(1,0,bF0); BARX();
    STAGEH(0, 1,1, A, m0, kB);
    VMW(8);
    BARX(); MM(1,1,bF1); BARX();
  }
  LOADA(0,0); LOADB(bF0, 0,0);
  BARX(); MM(0,0,bF0); BARX();
  LOADB(bF1, 0,1);
  BARX(); MM(0,1,bF1); BARX();
  LOADA(0,1);
  BARX(); MM(1,0,bF0); BARX();
  VMW(0);
  BARX(); MM(1,1,bF1); BARX();
  LOADA(1,0); LOADB(bF0, 1,0);
  BARX(); MM(0,0,bF0); BARX();
  LOADB(bF1, 1,1);
  BARX(); MM(0,1,bF1); BARX();
  LOADA(1,1);
  BARX(); MM(1,0,bF0); BARX();
  BARX(); MM(1,1,bF1); BARX();

  const int crow = lhi * 4;
#pragma unroll
  for (int mh = 0; mh < 2; ++mh)
#pragma unroll
    for (int nh = 0; nh < 2; ++nh)
#pragma unroll
      for (int m_ = 0; m_ < 4; ++m_)
#pragma unroll
        for (int n_ = 0; n_ < 2; ++n_) {
          float* cp = C + (size_t)(m0 + mh*128 + wm*64 + m_*16 + crow) * DIM
                        + (n0 + nh*128 + wn*32 + n_*16 + l15);
#pragma unroll
          for (int j2 = 0; j2 < 4; ++j2)
            cp[(size_t)j2 * DIM] = acc[mh][nh][m_][n_][j2];
        }
}

// ---------------- launch -------------------------------------------------------
extern "C" void kernel_launch(void* const* d_in, const int* in_sizes, int n_in,
                              void* d_out, int out_size, void* d_ws, size_t ws_size,
                              hipStream_t stream) {
  const float* x    = (const float*)d_in[0];
  const float* qry  = (const float*)d_in[1];
  const float* kvs  = (const float*)d_in[2];
  const float* wout = (const float*)d_in[3];
  float* out = (float*)d_out;

  char* ws = (char*)d_ws;
  size_t off = 0;
  float2* xhat = (float2*)(ws + off);
  off += (size_t)ROWS * NFP * sizeof(float2);           // 134.5 MB
  off = (off + 255) & ~(size_t)255;
  unsigned short* vbf = (unsigned short*)(ws + off);    // 67 MB
  // partial aliases vbf: partial dead before fft_inv writes vbf (stream-ordered)
  float2* partial = (float2*)(ws + off);                // 2.1 MB < 67 MB
  off += (size_t)ROWS * DIM * sizeof(unsigned short);
  off = (off + 255) & ~(size_t)255;
  unsigned short* wbf = (unsigned short*)(ws + off);    // 8.4 MB

  hipLaunchKernelGGL(w_to_bf16,   dim3((DIM*DIM)/(256*4)), dim3(256), 0, stream, wout, wbf);
  hipLaunchKernelGGL(fft_fwd,     dim3(ROWS),              dim3(256), 0, stream, x, xhat);
  hipLaunchKernelGGL(scan_partial,dim3(BATCH*NSC*PFB),     dim3(256), 0, stream, xhat, kvs, partial);
  hipLaunchKernelGGL(scan_offsets,dim3(BATCH*PFB),         dim3(256), 0, stream, partial);
  hipLaunchKernelGGL(scan_apply,  dim3(BATCH*NSC*PFB),     dim3(256), 0, stream, xhat, kvs, qry, partial);
  hipLaunchKernelGGL(fft_inv,     dim3(ROWS),              dim3(256), 0, stream, xhat, vbf);
  hipLaunchKernelGGL(gemm256,     dim3((ROWS/256)*(DIM/256)), dim3(512), 0, stream, vbf, wbf, out);
}

// Round 4
// 307.415 us; speedup vs baseline: 1.5294x; 1.0316x over previous
//
#include <hip/hip_runtime.h>
#include <hip/hip_bf16.h>
#include <stdint.h>

#define BATCH 4
#define SEQ   4096
#define DIM   2048
#define NFREQ 1025
#define NCPLX 1024
#define ROWS  (BATCH*SEQ)   // 16384

// fused chunk decomposition
#define SCH 32             // rows per block (sequential, cumsum in regs)
#define NSC (SEQ/SCH)      // 128 chunks per batch

typedef __bf16 bf16x8 __attribute__((ext_vector_type(8)));
typedef float  f32x4  __attribute__((ext_vector_type(4)));

__device__ __forceinline__ int drev4(int n) {  // reverse 5 base-4 digits of 10-bit n
  return ((n&3)<<8) | (((n>>2)&3)<<6) | (((n>>4)&3)<<4) | (((n>>6)&3)<<2) | ((n>>8)&3);
}
#define ZI(i) ((i) + ((i)>>4))   // LDS pad: every 16 float2 -> +1 (caps conflicts ~4-way)

__device__ __forceinline__ float2 cmulf(float2 a, float2 b) {
  return make_float2(a.x*b.x - a.y*b.y, a.x*b.y + a.y*b.x);
}

__device__ __forceinline__ unsigned short f2bf(float f) {
  union { float f; unsigned u; } v; v.f = f;
  unsigned r = v.u + 0x7fffu + ((v.u >> 16) & 1u);
  return (unsigned short)(r >> 16);
}

// ---------------- radix-4 1024-pt in-place DIT, precomputed stage twiddles ----
// tw1[s] = e^{-2pi i j / 4q} for this thread (fwd); INV uses conj.
template<int INV>
__device__ __forceinline__ void fft_stages_tw(float2* z, int tid, const float2* tw1) {
  { // stage q=1 (no twiddles)
    int b4 = tid*4;
    float2 x0=z[ZI(b4)], x1=z[ZI(b4+1)], x2=z[ZI(b4+2)], x3=z[ZI(b4+3)];
    float2 a = make_float2(x0.x+x2.x, x0.y+x2.y), b = make_float2(x0.x-x2.x, x0.y-x2.y);
    float2 c = make_float2(x1.x+x3.x, x1.y+x3.y), d = make_float2(x1.x-x3.x, x1.y-x3.y);
    z[ZI(b4)]   = make_float2(a.x+c.x, a.y+c.y);
    z[ZI(b4+2)] = make_float2(a.x-c.x, a.y-c.y);
    if (!INV) { z[ZI(b4+1)] = make_float2(b.x+d.y, b.y-d.x);
                z[ZI(b4+3)] = make_float2(b.x-d.y, b.y+d.x); }
    else      { z[ZI(b4+1)] = make_float2(b.x-d.y, b.y+d.x);
                z[ZI(b4+3)] = make_float2(b.x+d.y, b.y-d.x); }
  }
  __syncthreads();
#pragma unroll
  for (int s = 0; s < 4; ++s) {
    const int lq = 2 + 2*s;          // q = 4,16,64,256
    const int q  = 1 << lq;
    int j = tid & (q-1), g = tid >> lq;
    int base = (g << (lq+2)) + j;
    float2 w1 = tw1[s]; if (INV) w1.y = -w1.y;
    float2 w2 = cmulf(w1, w1), w3 = cmulf(w2, w1);
    float2 x0 = z[ZI(base)];
    float2 x1 = cmulf(z[ZI(base+q)],   w1);
    float2 x2 = cmulf(z[ZI(base+2*q)], w2);
    float2 x3 = cmulf(z[ZI(base+3*q)], w3);
    float2 a = make_float2(x0.x+x2.x, x0.y+x2.y), b = make_float2(x0.x-x2.x, x0.y-x2.y);
    float2 c = make_float2(x1.x+x3.x, x1.y+x3.y), d = make_float2(x1.x-x3.x, x1.y-x3.y);
    z[ZI(base)]     = make_float2(a.x+c.x, a.y+c.y);
    z[ZI(base+2*q)] = make_float2(a.x-c.x, a.y-c.y);
    if (!INV) { z[ZI(base+q)]   = make_float2(b.x+d.y, b.y-d.x);
                z[ZI(base+3*q)] = make_float2(b.x-d.y, b.y+d.x); }
    else      { z[ZI(base+q)]   = make_float2(b.x-d.y, b.y+d.x);
                z[ZI(base+3*q)] = make_float2(b.x+d.y, b.y-d.x); }
    __syncthreads();
  }
}

__device__ __forceinline__ void make_twiddles(int tid, float2* tw1, float2* upk) {
#pragma unroll
  for (int s = 0; s < 4; ++s) {
    const int lq = 2 + 2*s;
    const int q  = 1 << lq;
    int j = tid & (q-1);
    float ang = -6.2831853071795864769f * (float)j / (float)(4*q);
    float sw, cw; __sincosf(ang, &sw, &cw);
    tw1[s] = make_float2(cw, sw);
  }
#pragma unroll
  for (int i = 0; i < 4; ++i) {
    int k = tid + 256*i;
    float ang = -3.14159265358979323846f * (float)k / 1024.0f;
    float sw, cw; __sincosf(ang, &sw, &cw);
    upk[i] = make_float2(cw, sw);                     // e^{-i pi k/1024}
  }
}

// ============ fwd_fused: per-chunk FFT of 32 rows + kv partial sums ===========
__global__ __launch_bounds__(256) void fwd_fused(const float* __restrict__ x,
                                                 const float* __restrict__ kvs,
                                                 float2* __restrict__ partial) {
  __shared__ float2 z[ZI(1023)+2];
  const int tid = threadIdx.x;
  const int sc = blockIdx.x & (NSC-1), b = blockIdx.x >> 7;

  float2 tw1[4], upk[4];
  make_twiddles(tid, tw1, upk);
  int id0 = ZI(drev4(2*tid)),     id1 = ZI(drev4(2*tid+1));
  int id2 = ZI(drev4(2*tid+512)), id3 = ZI(drev4(2*tid+513));

  float sum[4][2] = {};
  float sumN = 0.f;

  const float* xrow = x + ((size_t)b*SEQ + (size_t)sc*SCH) * DIM;
  float4 c0 = ((const float4*)xrow)[tid];
  float4 c1 = ((const float4*)xrow)[tid + 256];

  for (int s = 0; s < SCH; ++s) {
    float4 n0f, n1f;
    if (s+1 < SCH) {
      const float* nx = xrow + (size_t)(s+1)*DIM;
      n0f = ((const float4*)nx)[tid]; n1f = ((const float4*)nx)[tid + 256];
    }
    z[id0] = make_float2(c0.x, c0.y); z[id1] = make_float2(c0.z, c0.w);
    z[id2] = make_float2(c1.x, c1.y); z[id3] = make_float2(c1.z, c1.w);
    __syncthreads();
    fft_stages_tw<0>(z, tid, tw1);
#pragma unroll
    for (int i = 0; i < 4; ++i) {
      int k = tid + 256*i;
      float2 Zk = z[ZI(k)];
      float2 Zn = z[ZI((NCPLX - k) & (NCPLX-1))];
      float Er = 0.5f*(Zk.x + Zn.x), Ei = 0.5f*(Zk.y - Zn.y);
      float dr = 0.5f*(Zk.x - Zn.x), di = 0.5f*(Zk.y + Zn.y);
      float Or = di, Oi = -dr;
      float vr = Er + upk[i].x*Or - upk[i].y*Oi;
      float vi = Ei + upk[i].y*Or + upk[i].x*Oi;
      sum[i][0] += vr; sum[i][1] += vi;
    }
    if (tid == 0) { float2 Z0 = z[ZI(0)]; sumN += Z0.x - Z0.y; }
    __syncthreads();                                   // z dead before next scatter
    c0 = n0f; c1 = n1f;
  }
  float2* pp = partial + ((size_t)b*NSC + sc) * NFREQ;
#pragma unroll
  for (int i = 0; i < 4; ++i) {
    int k = tid + 256*i;
    float ks = kvs[k];
    pp[k] = make_float2(ks*sum[i][0], ks*sum[i][1]);
  }
  if (tid == 0) pp[NCPLX] = make_float2(kvs[NCPLX]*sumN, 0.f);
}

// ============ scan_offsets: exclusive scan over chunks (per-k) ================
__global__ __launch_bounds__(256) void scan_offsets(float2* __restrict__ partial) {
  int k = (blockIdx.x % 5) * 256 + threadIdx.x;
  int b = blockIdx.x / 5;
  if (k >= NFREQ) return;
  float2* p = partial + (size_t)b*NSC*NFREQ + k;
  float rr = 0.f, ri = 0.f;
#pragma unroll 8
  for (int sc = 0; sc < NSC; sc++) {
    float2 t = p[(size_t)sc*NFREQ];
    p[(size_t)sc*NFREQ] = make_float2(rr, ri);
    rr += t.x; ri += t.y;
  }
}

// ============ inv_fused: re-FFT rows + cumsum-apply + inverse FFT -> bf16 =====
__global__ __launch_bounds__(256) void inv_fused(const float* __restrict__ x,
                                                 const float* __restrict__ kvs,
                                                 const float* __restrict__ qs_,
                                                 const float2* __restrict__ partial,
                                                 unsigned short* __restrict__ v) {
  __shared__ float2 z[ZI(1023)+2];
  __shared__ float2 qvb[NFREQ];
  const int tid = threadIdx.x;
  const int sc = blockIdx.x & (NSC-1), b = blockIdx.x >> 7;

  float2 tw1[4], upk[4];
  make_twiddles(tid, tw1, upk);
  int id0 = ZI(drev4(2*tid)),     id1 = ZI(drev4(2*tid+1));
  int id2 = ZI(drev4(2*tid+512)), id3 = ZI(drev4(2*tid+513));
  int rid0 = ZI(drev4(tid)),       rid1 = ZI(drev4(tid+256));
  int rid2 = ZI(drev4(tid+512)),   rid3 = ZI(drev4(tid+768));

  // per-k params + cumsum state (init = exclusive chunk offset)
  float ksv[4], qsv[4], cr[4], ci[4];
  const float2* pp = partial + ((size_t)b*NSC + sc) * NFREQ;
#pragma unroll
  for (int i = 0; i < 4; ++i) {
    int k = tid + 256*i;
    ksv[i] = kvs[k]; qsv[i] = qs_[k];
    float2 o = pp[k]; cr[i] = o.x; ci[i] = o.y;
  }
  float ksN = kvs[NCPLX], qsN = qs_[NCPLX], crN = pp[NCPLX].x;

  const float* xrow = x + ((size_t)b*SEQ + (size_t)sc*SCH) * DIM;
  unsigned* vrow = (unsigned*)(v + (((size_t)b*SEQ + (size_t)sc*SCH)) * DIM);
  float4 c0 = ((const float4*)xrow)[tid];
  float4 c1 = ((const float4*)xrow)[tid + 256];

  for (int s = 0; s < SCH; ++s) {
    float4 n0f, n1f;
    if (s+1 < SCH) {
      const float* nx = xrow + (size_t)(s+1)*DIM;
      n0f = ((const float4*)nx)[tid]; n1f = ((const float4*)nx)[tid + 256];
    }
    // forward FFT of this row
    z[id0] = make_float2(c0.x, c0.y); z[id1] = make_float2(c0.z, c0.w);
    z[id2] = make_float2(c1.x, c1.y); z[id3] = make_float2(c1.z, c1.w);
    __syncthreads();
    fft_stages_tw<0>(z, tid, tw1);
    // unpack -> cumsum -> qv into LDS
#pragma unroll
    for (int i = 0; i < 4; ++i) {
      int k = tid + 256*i;
      float2 Zk = z[ZI(k)];
      float2 Zn = z[ZI((NCPLX - k) & (NCPLX-1))];
      float Er = 0.5f*(Zk.x + Zn.x), Ei = 0.5f*(Zk.y - Zn.y);
      float dr = 0.5f*(Zk.x - Zn.x), di = 0.5f*(Zk.y + Zn.y);
      float Or = di, Oi = -dr;
      float vr = Er + upk[i].x*Or - upk[i].y*Oi;
      float vi = Ei + upk[i].y*Or + upk[i].x*Oi;
      cr[i] += vr * ksv[i]; ci[i] += vi * ksv[i];      // inclusive cumsum of kv
      qvb[k] = make_float2(qsv[i]*(vr*cr[i] - vi*ci[i]),
                           qsv[i]*(vr*ci[i] + vi*cr[i]));
    }
    if (tid == 0) {
      float2 Z0 = z[ZI(0)];
      float vN = Z0.x - Z0.y;
      crN += vN * ksN;
      qvb[NCPLX] = make_float2(qsN * vN * crN, 0.f);
    }
    __syncthreads();
    // inverse preprocessing: qvb -> z (digit-reversed), conj twiddle of upk
#pragma unroll
    for (int i = 0; i < 4; ++i) {
      int k = tid + 256*i;
      float2 Xk = qvb[k];
      float2 Xn = qvb[NCPLX - k];
      float Er = 0.5f*(Xk.x + Xn.x), Ei = 0.5f*(Xk.y - Xn.y);
      float dr = 0.5f*(Xk.x - Xn.x), di = 0.5f*(Xk.y + Xn.y);
      float cw = upk[i].x, sw = -upk[i].y;             // e^{+i pi k/1024}
      float Or = dr*cw - di*sw, Oi = dr*sw + di*cw;
      const float scl = 1.0f/1024.0f;
      float2 val = make_float2(scl*(Er - Oi), scl*(Ei + Or));
      if (i == 0) z[rid0] = val;
      else if (i == 1) z[rid1] = val;
      else if (i == 2) z[rid2] = val;
      else z[rid3] = val;
    }
    __syncthreads();
    fft_stages_tw<1>(z, tid, tw1);
    // write bf16 row
    unsigned* vr32 = vrow + (size_t)s * (DIM/2);
#pragma unroll
    for (int i = 0; i < 4; ++i) {
      int n = tid + 256*i;
      float2 t = z[ZI(n)];
      vr32[n] = (unsigned)f2bf(t.x) | ((unsigned)f2bf(t.y) << 16);
    }
    __syncthreads();
    c0 = n0f; c1 = n1f;
  }
}

// ---------------- w fp32 -> bf16 ----------------------------------------------
__global__ __launch_bounds__(256) void w_to_bf16(const float* __restrict__ w,
                                                 unsigned short* __restrict__ wb) {
  size_t idx = (size_t)blockIdx.x * 256 + threadIdx.x;
  float4 v = ((const float4*)w)[idx];
  uint2 o;
  o.x = (unsigned)f2bf(v.x) | ((unsigned)f2bf(v.y) << 16);
  o.y = (unsigned)f2bf(v.z) | ((unsigned)f2bf(v.w) << 16);
  ((uint2*)wb)[idx] = o;
}

// ============ 256x256 8-phase GEMM: C[M,N] = A[M,K] * B[N,K]^T, bf16->fp32 =====
#define NKT (DIM/64)      // 32 K-tiles
#define NIT (NKT/2)       // 16 iterations of 2 K-tiles

#define BARX() do{ __builtin_amdgcn_s_barrier(); __builtin_amdgcn_sched_barrier(0); }while(0)
#define VMW(N) do{ asm volatile("s_waitcnt vmcnt(" #N ")" ::: "memory"); __builtin_amdgcn_sched_barrier(0); }while(0)

#define LOADA(B_, MH) do{ _Pragma("unroll") for (int m_=0;m_<4;++m_) _Pragma("unroll") for (int kk_=0;kk_<2;++kk_){ \
    int rA_ = wm*64 + m_*16 + l15; \
    aF[m_][kk_] = *(const bf16x8*)(smem + ((B_)*2+(MH))*16384 + rA_*128 + ((kk_*64 + lhi*16) ^ ((rA_&7)<<4))); } }while(0)

#define LOADB(DST, B_, NH) do{ _Pragma("unroll") for (int n_=0;n_<2;++n_) _Pragma("unroll") for (int kk_=0;kk_<2;++kk_){ \
    int rB_ = wn*32 + n_*16 + l15; \
    DST[n_][kk_] = *(const bf16x8*)(smem + 65536 + ((B_)*2+(NH))*16384 + rB_*128 + ((kk_*64 + lhi*16) ^ ((rB_&7)<<4))); } }while(0)

#define MM(MH, NH, BF) do{ __builtin_amdgcn_s_setprio(1); \
    _Pragma("unroll") for (int kk_=0;kk_<2;++kk_) _Pragma("unroll") for (int m_=0;m_<4;++m_) _Pragma("unroll") for (int n_=0;n_<2;++n_) \
      acc[MH][NH][m_][n_] = __builtin_amdgcn_mfma_f32_16x16x32_bf16(aF[m_][kk_], BF[n_][kk_], acc[MH][NH][m_][n_], 0, 0, 0); \
    __builtin_amdgcn_s_setprio(0); }while(0)

#define STAGEH(REG, B_, H_, GP, ROW0, KT) do{ _Pragma("unroll") for (int c_=0;c_<2;++c_){ \
    int ci_ = c_*512 + tid; int r_ = ci_>>3, sl_ = ci_&7; \
    const unsigned short* sp_ = (GP) + (size_t)((ROW0) + (H_)*128 + r_)*DIM + (KT) + ((sl_ ^ (r_&7))*8); \
    __builtin_amdgcn_global_load_lds((const __attribute__((address_space(1))) void*)sp_, \
      (__attribute__((address_space(3))) void*)(smem + (REG) + ((B_)*2+(H_))*16384 + ci_*16), 16, 0, 0); } }while(0)

__global__ __launch_bounds__(512, 2) void gemm256(const unsigned short* __restrict__ A,
                                                  const unsigned short* __restrict__ B,
                                                  float* __restrict__ C) {
  __shared__ __align__(16) char smem[131072];
  const int tid = threadIdx.x;
  const int lane = tid & 63;
  const int wid  = tid >> 6;
  const int wm = wid >> 2, wn = wid & 3;
  const int l15 = lane & 15, lhi = lane >> 4;

  const int bn = blockIdx.x & 7, bm = blockIdx.x >> 3;
  const int m0 = bm * 256, n0 = bn * 256;

  f32x4 acc[2][2][4][2] = {};
  bf16x8 aF[4][2], bF0[2][2], bF1[2][2];

  STAGEH(0,     0,0, A, m0, 0);  STAGEH(65536, 0,0, B, n0, 0);
  STAGEH(65536, 0,1, B, n0, 0);  STAGEH(0,     0,1, A, m0, 0);
  STAGEH(0,     1,0, A, m0, 64); STAGEH(65536, 1,0, B, n0, 64);
  STAGEH(65536, 1,1, B, n0, 64); STAGEH(0,     1,1, A, m0, 64);
  VMW(8);
  BARX();

#pragma unroll 1
  for (int j = 0; j < NIT-1; ++j) {
    const int kA = (2*j+2)*64, kB = (2*j+3)*64;
    LOADA(0,0); LOADB(bF0, 0,0);
    BARX(); MM(0,0,bF0); BARX();
    LOADB(bF1, 0,1);
    STAGEH(0, 0,0, A, m0, kA); STAGEH(65536, 0,0, B, n0, kA);
    BARX(); MM(0,1,bF1); BARX();
    LOADA(0,1);
    STAGEH(65536, 0,1, B, n0, kA);
    BARX(); MM(1,0,bF0); BARX();
    STAGEH(0, 0,1, A, m0, kA);
    VMW(8);
    BARX(); MM(1,1,bF1); BARX();
    LOADA(1,0); LOADB(bF0, 1,0);
    BARX(); MM(0,0,bF0); BARX();
    LOADB(bF1, 1,1);
    STAGEH(0, 1,0, A, m0, kB); STAGEH(65536, 1,0, B, n0, kB);
    BARX(); MM(0,1,bF1); BARX();
    LOADA(1,1);
    STAGEH(65536, 1,1, B, n0, kB);
    BARX(); MM(1,0,bF0); BARX();
    STAGEH(0, 1,1, A, m0, kB);
    VMW(8);
    BARX(); MM(1,1,bF1); BARX();
  }
  LOADA(0,0); LOADB(bF0, 0,0);
  BARX(); MM(0,0,bF0); BARX();
  LOADB(bF1, 0,1);
  BARX(); MM(0,1,bF1); BARX();
  LOADA(0,1);
  BARX(); MM(1,0,bF0); BARX();
  VMW(0);
  BARX(); MM(1,1,bF1); BARX();
  LOADA(1,0); LOADB(bF0, 1,0);
  BARX(); MM(0,0,bF0); BARX();
  LOADB(bF1, 1,1);
  BARX(); MM(0,1,bF1); BARX();
  LOADA(1,1);
  BARX(); MM(1,0,bF0); BARX();
  BARX(); MM(1,1,bF1); BARX();

  const int crow = lhi * 4;
#pragma unroll
  for (int mh = 0; mh < 2; ++mh)
#pragma unroll
    for (int nh = 0; nh < 2; ++nh)
#pragma unroll
      for (int m_ = 0; m_ < 4; ++m_)
#pragma unroll
        for (int n_ = 0; n_ < 2; ++n_) {
          float* cp = C + (size_t)(m0 + mh*128 + wm*64 + m_*16 + crow) * DIM
                        + (n0 + nh*128 + wn*32 + n_*16 + l15);
#pragma unroll
          for (int j2 = 0; j2 < 4; ++j2)
            cp[(size_t)j2 * DIM] = acc[mh][nh][m_][n_][j2];
        }
}

// ---------------- launch -------------------------------------------------------
extern "C" void kernel_launch(void* const* d_in, const int* in_sizes, int n_in,
                              void* d_out, int out_size, void* d_ws, size_t ws_size,
                              hipStream_t stream) {
  const float* x    = (const float*)d_in[0];
  const float* qry  = (const float*)d_in[1];
  const float* kvs  = (const float*)d_in[2];
  const float* wout = (const float*)d_in[3];
  float* out = (float*)d_out;

  char* ws = (char*)d_ws;
  size_t off = 0;
  unsigned short* vbf = (unsigned short*)(ws + off);    // 67 MB
  off += (size_t)ROWS * DIM * sizeof(unsigned short);
  off = (off + 255) & ~(size_t)255;
  unsigned short* wbf = (unsigned short*)(ws + off);    // 8.4 MB
  off += (size_t)DIM * DIM * sizeof(unsigned short);
  off = (off + 255) & ~(size_t)255;
  float2* partial = (float2*)(ws + off);                // 4.2 MB
  off += (size_t)BATCH * NSC * NFREQ * sizeof(float2);

  hipLaunchKernelGGL(w_to_bf16,   dim3((DIM*DIM)/(256*4)), dim3(256), 0, stream, wout, wbf);
  hipLaunchKernelGGL(fwd_fused,   dim3(BATCH*NSC),         dim3(256), 0, stream, x, kvs, partial);
  hipLaunchKernelGGL(scan_offsets,dim3(BATCH*5),           dim3(256), 0, stream, partial);
  hipLaunchKernelGGL(inv_fused,   dim3(BATCH*NSC),         dim3(256), 0, stream, x, kvs, qry, partial, vbf);
  hipLaunchKernelGGL(gemm256,     dim3((ROWS/256)*(DIM/256)), dim3(512), 0, stream, vbf, wbf, out);
}

// Round 5
// 248.554 us; speedup vs baseline: 1.8916x; 1.2368x over previous
//
#include <hip/hip_runtime.h>
#include <hip/hip_bf16.h>
#include <stdint.h>

#define BATCH 4
#define SEQ   4096
#define DIM   2048
#define NFREQ 1025
#define NCPLX 1024
#define ROWS  (BATCH*SEQ)   // 16384

// fused chunk decomposition
#define SCH  16            // rows per block (sequential, cumsum in regs)
#define NSC  (SEQ/SCH)     // 256 chunks per batch
#define NSCG 16            // chunks per scan group
#define NGRP (NSC/NSCG)    // 16 groups

#define SPEC_STRIDE 257    // uint4 per row: 256 pair-packed + 1 extra (k=512)

typedef __bf16 bf16x8 __attribute__((ext_vector_type(8)));
typedef float  f32x4  __attribute__((ext_vector_type(4)));

__device__ __forceinline__ int drev4(int n) {  // reverse 5 base-4 digits of 10-bit n
  return ((n&3)<<8) | (((n>>2)&3)<<6) | (((n>>4)&3)<<4) | (((n>>6)&3)<<2) | ((n>>8)&3);
}
#define ZI(i) ((i) + ((i)>>4))   // LDS pad: every 16 float2 -> +1 (caps conflicts ~4-way)

__device__ __forceinline__ float2 cmulf(float2 a, float2 b) {
  return make_float2(a.x*b.x - a.y*b.y, a.x*b.y + a.y*b.x);
}

__device__ __forceinline__ unsigned short f2bf(float f) {
  union { float f; unsigned u; } v; v.f = f;
  unsigned r = v.u + 0x7fffu + ((v.u >> 16) & 1u);
  return (unsigned short)(r >> 16);
}
__device__ __forceinline__ unsigned packbf(float2 v) {
  return (unsigned)f2bf(v.x) | ((unsigned)f2bf(v.y) << 16);
}
__device__ __forceinline__ float2 unpackbf(unsigned u) {
  union { unsigned u; float f; } a, b;
  a.u = u << 16; b.u = u & 0xffff0000u;
  return make_float2(a.f, b.f);
}

// ---------------- radix-4 1024-pt in-place DIT, precomputed stage twiddles ----
template<int INV>
__device__ __forceinline__ void fft_stages_tw(float2* z, int tid, const float2* tw1) {
  { // stage q=1 (no twiddles)
    int b4 = tid*4;
    float2 x0=z[ZI(b4)], x1=z[ZI(b4+1)], x2=z[ZI(b4+2)], x3=z[ZI(b4+3)];
    float2 a = make_float2(x0.x+x2.x, x0.y+x2.y), b = make_float2(x0.x-x2.x, x0.y-x2.y);
    float2 c = make_float2(x1.x+x3.x, x1.y+x3.y), d = make_float2(x1.x-x3.x, x1.y-x3.y);
    z[ZI(b4)]   = make_float2(a.x+c.x, a.y+c.y);
    z[ZI(b4+2)] = make_float2(a.x-c.x, a.y-c.y);
    if (!INV) { z[ZI(b4+1)] = make_float2(b.x+d.y, b.y-d.x);
                z[ZI(b4+3)] = make_float2(b.x-d.y, b.y+d.x); }
    else      { z[ZI(b4+1)] = make_float2(b.x-d.y, b.y+d.x);
                z[ZI(b4+3)] = make_float2(b.x+d.y, b.y-d.x); }
  }
  __syncthreads();
#pragma unroll
  for (int s = 0; s < 4; ++s) {
    const int lq = 2 + 2*s;          // q = 4,16,64,256
    const int q  = 1 << lq;
    int j = tid & (q-1), g = tid >> lq;
    int base = (g << (lq+2)) + j;
    float2 w1 = tw1[s]; if (INV) w1.y = -w1.y;
    float2 w2 = cmulf(w1, w1), w3 = cmulf(w2, w1);
    float2 x0 = z[ZI(base)];
    float2 x1 = cmulf(z[ZI(base+q)],   w1);
    float2 x2 = cmulf(z[ZI(base+2*q)], w2);
    float2 x3 = cmulf(z[ZI(base+3*q)], w3);
    float2 a = make_float2(x0.x+x2.x, x0.y+x2.y), b = make_float2(x0.x-x2.x, x0.y-x2.y);
    float2 c = make_float2(x1.x+x3.x, x1.y+x3.y), d = make_float2(x1.x-x3.x, x1.y-x3.y);
    z[ZI(base)]     = make_float2(a.x+c.x, a.y+c.y);
    z[ZI(base+2*q)] = make_float2(a.x-c.x, a.y-c.y);
    if (!INV) { z[ZI(base+q)]   = make_float2(b.x+d.y, b.y-d.x);
                z[ZI(base+3*q)] = make_float2(b.x-d.y, b.y+d.x); }
    else      { z[ZI(base+q)]   = make_float2(b.x-d.y, b.y+d.x);
                z[ZI(base+3*q)] = make_float2(b.x+d.y, b.y-d.x); }
    __syncthreads();
  }
}

__device__ __forceinline__ void make_tw1(int tid, float2* tw1) {
#pragma unroll
  for (int s = 0; s < 4; ++s) {
    const int lq = 2 + 2*s;
    const int q  = 1 << lq;
    int j = tid & (q-1);
    float ang = -6.2831853071795864769f * (float)j / (float)(4*q);
    float sw, cw; __sincosf(ang, &sw, &cw);
    tw1[s] = make_float2(cw, sw);
  }
}

// ============ fwd_fused: FFT 16 rows, store bf16 spectrum + kv partial sums ===
// Pair-packed spectrum: spec[row][t] = {v[t], v[1024-t], v[t+256], v[768-t]}
// (bf16 complex each); extra slot [256].x = v[512].
__global__ __launch_bounds__(256) void fwd_fused(const float* __restrict__ x,
                                                 const float* __restrict__ kvs,
                                                 uint4* __restrict__ spec,
                                                 float2* __restrict__ partial) {
  __shared__ float2 z[ZI(1023)+2];
  const int tid = threadIdx.x;
  const int sc = blockIdx.x & (NSC-1), b = blockIdx.x >> 8;

  float2 tw1[4];
  make_tw1(tid, tw1);
  const int kA = tid, kB = tid + 256;
  float swA, cwA, swB, cwB;   // w = e^{-i pi k/1024}
  __sincosf(-3.14159265358979323846f * (float)kA / 1024.0f, &swA, &cwA);
  __sincosf(-3.14159265358979323846f * (float)kB / 1024.0f, &swB, &cwB);
  int id0 = ZI(drev4(2*tid)),     id1 = ZI(drev4(2*tid+1));
  int id2 = ZI(drev4(2*tid+512)), id3 = ZI(drev4(2*tid+513));

  float2 sA={0,0}, sAp={0,0}, sB={0,0}, sBp={0,0}, s5={0,0};

  const size_t row0 = (size_t)b*SEQ + (size_t)sc*SCH;
  const float* xrow = x + row0*DIM;
  float4 c0 = ((const float4*)xrow)[tid];
  float4 c1 = ((const float4*)xrow)[tid + 256];

  for (int s = 0; s < SCH; ++s) {
    float4 n0f, n1f;
    if (s+1 < SCH) {
      const float* nx = xrow + (size_t)(s+1)*DIM;
      n0f = ((const float4*)nx)[tid]; n1f = ((const float4*)nx)[tid + 256];
    }
    z[id0] = make_float2(c0.x, c0.y); z[id1] = make_float2(c0.z, c0.w);
    z[id2] = make_float2(c1.x, c1.y); z[id3] = make_float2(c1.z, c1.w);
    __syncthreads();
    fft_stages_tw<0>(z, tid, tw1);
    float2 ZkA = z[ZI(kA)], ZnA = z[ZI((NCPLX - kA) & (NCPLX-1))];
    float2 ZkB = z[ZI(kB)], ZnB = z[ZI(768 - tid)];
    // pair unpack A: v[kA], v[1024-kA]
    float Er = 0.5f*(ZkA.x + ZnA.x), Ei = 0.5f*(ZkA.y - ZnA.y);
    float dr = 0.5f*(ZkA.x - ZnA.x), di = 0.5f*(ZkA.y + ZnA.y);
    float2 vA  = make_float2( Er + cwA*di + swA*dr,  Ei + swA*di - cwA*dr);
    float2 vAp = make_float2( Er - cwA*di - swA*dr, -Ei + swA*di - cwA*dr);
    // pair unpack B: v[kB], v[768-tid]
    float Fr = 0.5f*(ZkB.x + ZnB.x), Fi = 0.5f*(ZkB.y - ZnB.y);
    float er = 0.5f*(ZkB.x - ZnB.x), ei = 0.5f*(ZkB.y + ZnB.y);
    float2 vB  = make_float2( Fr + cwB*ei + swB*er,  Fi + swB*ei - cwB*er);
    float2 vBp = make_float2( Fr - cwB*ei - swB*er, -Fi + swB*ei - cwB*er);
    sA.x += vA.x;  sA.y += vA.y;   sAp.x += vAp.x; sAp.y += vAp.y;
    sB.x += vB.x;  sB.y += vB.y;   sBp.x += vBp.x; sBp.y += vBp.y;
    uint4* sprow = spec + (row0 + s) * SPEC_STRIDE;
    sprow[tid] = make_uint4(packbf(vA), packbf(vAp), packbf(vB), packbf(vBp));
    if (tid == 0) {
      float2 Z5 = z[ZI(512)];
      float2 v5 = make_float2(Z5.x, -Z5.y);
      s5.x += v5.x; s5.y += v5.y;
      ((unsigned*)(sprow + 256))[0] = packbf(v5);
    }
    __syncthreads();                                   // z free for next scatter
    c0 = n0f; c1 = n1f;
  }
  float2* pp = partial + ((size_t)(b*NSC + sc)) * NFREQ;
  float kvA = kvs[kA], kvAp = kvs[NCPLX - kA], kvB = kvs[kB], kvBp = kvs[768 - tid];
  pp[kA]          = make_float2(kvA*sA.x,  kvA*sA.y);
  pp[NCPLX - kA]  = make_float2(kvAp*sAp.x, kvAp*sAp.y);
  pp[kB]          = make_float2(kvB*sB.x,  kvB*sB.y);
  pp[768 - tid]   = make_float2(kvBp*sBp.x, kvBp*sBp.y);
  if (tid == 0) { float kv5 = kvs[512]; pp[512] = make_float2(kv5*s5.x, kv5*s5.y); }
}

// ============ 2-level chunk scan ==============================================
__global__ __launch_bounds__(256) void scanA(float2* __restrict__ partial,
                                             float2* __restrict__ gtot) {
  int kc = blockIdx.x % 5, g = (blockIdx.x / 5) % NGRP, b = blockIdx.x / (5*NGRP);
  int k = kc*256 + threadIdx.x;
  if (k >= NFREQ) return;
  float2* p = partial + ((size_t)(b*NSC + g*NSCG)) * NFREQ + k;
  float2 run = {0.f, 0.f};
#pragma unroll
  for (int i = 0; i < NSCG; ++i) {
    float2 t = p[(size_t)i*NFREQ];
    p[(size_t)i*NFREQ] = run;                          // exclusive within group
    run.x += t.x; run.y += t.y;
  }
  gtot[((size_t)(b*NGRP + g)) * NFREQ + k] = run;
}

__global__ __launch_bounds__(256) void scanB(float2* __restrict__ gtot) {
  int kc = blockIdx.x % 5, b = blockIdx.x / 5;
  int k = kc*256 + threadIdx.x;
  if (k >= NFREQ) return;
  float2* p = gtot + ((size_t)b*NGRP) * NFREQ + k;
  float2 run = {0.f, 0.f};
#pragma unroll
  for (int g = 0; g < NGRP; ++g) {
    float2 t = p[(size_t)g*NFREQ];
    p[(size_t)g*NFREQ] = run;                          // exclusive across groups
    run.x += t.x; run.y += t.y;
  }
}

// ============ inv_fused: load spectrum + cumsum-apply + inverse FFT -> bf16 ===
__global__ __launch_bounds__(256) void inv_fused(const uint4* __restrict__ spec,
                                                 const float* __restrict__ kvs,
                                                 const float* __restrict__ qs_,
                                                 const float2* __restrict__ partial,
                                                 const float2* __restrict__ gtot,
                                                 unsigned short* __restrict__ vout) {
  __shared__ float2 z[ZI(1023)+2];
  const int tid = threadIdx.x;
  const int sc = blockIdx.x & (NSC-1), b = blockIdx.x >> 8;

  float2 tw1[4];
  make_tw1(tid, tw1);
  const int kA = tid, kB = tid + 256;
  float swA, cwA, swB, cwB;   // w' = e^{+i pi k/1024}
  __sincosf(3.14159265358979323846f * (float)kA / 1024.0f, &swA, &cwA);
  __sincosf(3.14159265358979323846f * (float)kB / 1024.0f, &swB, &cwB);
  int ridA  = ZI(drev4(kA));
  int ridAp = ZI(drev4((NCPLX - kA) & (NCPLX-1)));
  int ridB  = ZI(drev4(kB));
  int ridBp = ZI(drev4(768 - tid));

  float ksA = kvs[kA], ksAp = kvs[NCPLX - kA], ksB = kvs[kB], ksBp = kvs[768 - tid];
  float qsA = qs_[kA], qsAp = qs_[NCPLX - kA], qsB = qs_[kB], qsBp = qs_[768 - tid];

  const float2* pp = partial + ((size_t)(b*NSC + sc)) * NFREQ;
  const float2* gp = gtot + ((size_t)(b*NGRP + (sc >> 4))) * NFREQ;
  float2 CA  = make_float2(pp[kA].x + gp[kA].x,                 pp[kA].y + gp[kA].y);
  float2 CAp = make_float2(pp[NCPLX-kA].x + gp[NCPLX-kA].x,     pp[NCPLX-kA].y + gp[NCPLX-kA].y);
  float2 CB  = make_float2(pp[kB].x + gp[kB].x,                 pp[kB].y + gp[kB].y);
  float2 CBp = make_float2(pp[768-tid].x + gp[768-tid].x,       pp[768-tid].y + gp[768-tid].y);
  float ks5 = kvs[512], qs5 = qs_[512];
  float2 C5 = make_float2(pp[512].x + gp[512].x, pp[512].y + gp[512].y);
  const int rid5 = ZI(drev4(512));

  const size_t row0 = (size_t)b*SEQ + (size_t)sc*SCH;
  const uint4* sprow = spec + row0 * SPEC_STRIDE;
  unsigned* vr = (unsigned*)(vout + row0 * DIM);
  uint4 sp = sprow[tid];
  unsigned spN = ((const unsigned*)(sprow + 256))[0];
  const float scl = 1.0f/1024.0f;

  for (int s = 0; s < SCH; ++s) {
    uint4 spn; unsigned spNn;
    if (s+1 < SCH) {
      const uint4* nr = sprow + (size_t)(s+1) * SPEC_STRIDE;
      spn = nr[tid]; spNn = ((const unsigned*)(nr + 256))[0];
    }
    float2 vA = unpackbf(sp.x), vAp = unpackbf(sp.y);
    float2 vB = unpackbf(sp.z), vBp = unpackbf(sp.w);
    // inclusive cumsum of kv + qv
    CA.x  += vA.x*ksA;   CA.y  += vA.y*ksA;
    CAp.x += vAp.x*ksAp; CAp.y += vAp.y*ksAp;
    CB.x  += vB.x*ksB;   CB.y  += vB.y*ksB;
    CBp.x += vBp.x*ksBp; CBp.y += vBp.y*ksBp;
    float2 qvA  = make_float2(qsA *(vA.x*CA.x  - vA.y*CA.y),  qsA *(vA.x*CA.y  + vA.y*CA.x));
    float2 qvAp = make_float2(qsAp*(vAp.x*CAp.x- vAp.y*CAp.y),qsAp*(vAp.x*CAp.y+ vAp.y*CAp.x));
    float2 qvB  = make_float2(qsB *(vB.x*CB.x  - vB.y*CB.y),  qsB *(vB.x*CB.y  + vB.y*CB.x));
    float2 qvBp = make_float2(qsBp*(vBp.x*CBp.x- vBp.y*CBp.y),qsBp*(vBp.x*CBp.y+ vBp.y*CBp.x));
    // pair inverse-prep A: val[kA], val[1024-kA] share terms
    float Er = 0.5f*(qvA.x + qvAp.x), Ei = 0.5f*(qvA.y - qvAp.y);
    float dr = 0.5f*(qvA.x - qvAp.x), di = 0.5f*(qvA.y + qvAp.y);
    float Or = dr*cwA - di*swA, Oi = dr*swA + di*cwA;
    float2 valA  = make_float2(scl*(Er - Oi), scl*( Ei + Or));
    float2 valAp = make_float2(scl*(Er + Oi), scl*(-Ei + Or));
    // pair inverse-prep B
    float Fr = 0.5f*(qvB.x + qvBp.x), Fi = 0.5f*(qvB.y - qvBp.y);
    float er = 0.5f*(qvB.x - qvBp.x), ei = 0.5f*(qvB.y + qvBp.y);
    float Pr = er*cwB - ei*swB, Pi = er*swB + ei*cwB;
    float2 valB  = make_float2(scl*(Fr - Pi), scl*( Fi + Pr));
    float2 valBp = make_float2(scl*(Fr + Pi), scl*(-Fi + Pr));
    z[ridA] = valA; z[ridAp] = valAp; z[ridB] = valB; z[ridBp] = valBp;
    if (tid == 0) {
      float2 v5 = unpackbf(spN);
      C5.x += v5.x*ks5; C5.y += v5.y*ks5;
      float2 qv5 = make_float2(qs5*(v5.x*C5.x - v5.y*C5.y), qs5*(v5.x*C5.y + v5.y*C5.x));
      z[rid5] = make_float2(scl*qv5.x, -scl*qv5.y);
    }
    __syncthreads();
    fft_stages_tw<1>(z, tid, tw1);
    unsigned* vr32 = vr + (size_t)s * (DIM/2);
#pragma unroll
    for (int i = 0; i < 4; ++i) {
      int n = tid + 256*i;
      float2 t2 = z[ZI(n)];
      vr32[n] = packbf(t2);
    }
    __syncthreads();
    sp = spn; spN = spNn;
  }
}

// ---------------- w fp32 -> bf16 ----------------------------------------------
__global__ __launch_bounds__(256) void w_to_bf16(const float* __restrict__ w,
                                                 unsigned short* __restrict__ wb) {
  size_t idx = (size_t)blockIdx.x * 256 + threadIdx.x;
  float4 v = ((const float4*)w)[idx];
  uint2 o;
  o.x = (unsigned)f2bf(v.x) | ((unsigned)f2bf(v.y) << 16);
  o.y = (unsigned)f2bf(v.z) | ((unsigned)f2bf(v.w) << 16);
  ((uint2*)wb)[idx] = o;
}

// ============ 256x256 8-phase GEMM: C[M,N] = A[M,K] * B[N,K]^T, bf16->fp32 =====
#define NKT (DIM/64)      // 32 K-tiles
#define NIT (NKT/2)       // 16 iterations of 2 K-tiles

#define BARX() do{ __builtin_amdgcn_s_barrier(); __builtin_amdgcn_sched_barrier(0); }while(0)
#define VMW(N) do{ asm volatile("s_waitcnt vmcnt(" #N ")" ::: "memory"); __builtin_amdgcn_sched_barrier(0); }while(0)

#define LOADA(B_, MH) do{ _Pragma("unroll") for (int m_=0;m_<4;++m_) _Pragma("unroll") for (int kk_=0;kk_<2;++kk_){ \
    int rA_ = wm*64 + m_*16 + l15; \
    aF[m_][kk_] = *(const bf16x8*)(smem + ((B_)*2+(MH))*16384 + rA_*128 + ((kk_*64 + lhi*16) ^ ((rA_&7)<<4))); } }while(0)

#define LOADB(DST, B_, NH) do{ _Pragma("unroll") for (int n_=0;n_<2;++n_) _Pragma("unroll") for (int kk_=0;kk_<2;++kk_){ \
    int rB_ = wn*32 + n_*16 + l15; \
    DST[n_][kk_] = *(const bf16x8*)(smem + 65536 + ((B_)*2+(NH))*16384 + rB_*128 + ((kk_*64 + lhi*16) ^ ((rB_&7)<<4))); } }while(0)

#define MM(MH, NH, BF) do{ __builtin_amdgcn_s_setprio(1); \
    _Pragma("unroll") for (int kk_=0;kk_<2;++kk_) _Pragma("unroll") for (int m_=0;m_<4;++m_) _Pragma("unroll") for (int n_=0;n_<2;++n_) \
      acc[MH][NH][m_][n_] = __builtin_amdgcn_mfma_f32_16x16x32_bf16(aF[m_][kk_], BF[n_][kk_], acc[MH][NH][m_][n_], 0, 0, 0); \
    __builtin_amdgcn_s_setprio(0); }while(0)

#define STAGEH(REG, B_, H_, GP, ROW0, KT) do{ _Pragma("unroll") for (int c_=0;c_<2;++c_){ \
    int ci_ = c_*512 + tid; int r_ = ci_>>3, sl_ = ci_&7; \
    const unsigned short* sp_ = (GP) + (size_t)((ROW0) + (H_)*128 + r_)*DIM + (KT) + ((sl_ ^ (r_&7))*8); \
    __builtin_amdgcn_global_load_lds((const __attribute__((address_space(1))) void*)sp_, \
      (__attribute__((address_space(3))) void*)(smem + (REG) + ((B_)*2+(H_))*16384 + ci_*16), 16, 0, 0); } }while(0)

__global__ __launch_bounds__(512, 2) void gemm256(const unsigned short* __restrict__ A,
                                                  const unsigned short* __restrict__ B,
                                                  float* __restrict__ C) {
  __shared__ __align__(16) char smem[131072];
  const int tid = threadIdx.x;
  const int lane = tid & 63;
  const int wid  = tid >> 6;
  const int wm = wid >> 2, wn = wid & 3;
  const int l15 = lane & 15, lhi = lane >> 4;

  const int bn = blockIdx.x & 7, bm = blockIdx.x >> 3;
  const int m0 = bm * 256, n0 = bn * 256;

  f32x4 acc[2][2][4][2] = {};
  bf16x8 aF[4][2], bF0[2][2], bF1[2][2];

  STAGEH(0,     0,0, A, m0, 0);  STAGEH(65536, 0,0, B, n0, 0);
  STAGEH(65536, 0,1, B, n0, 0);  STAGEH(0,     0,1, A, m0, 0);
  STAGEH(0,     1,0, A, m0, 64); STAGEH(65536, 1,0, B, n0, 64);
  STAGEH(65536, 1,1, B, n0, 64); STAGEH(0,     1,1, A, m0, 64);
  VMW(8);
  BARX();

#pragma unroll 1
  for (int j = 0; j < NIT-1; ++j) {
    const int kA = (2*j+2)*64, kB = (2*j+3)*64;
    LOADA(0,0); LOADB(bF0, 0,0);
    BARX(); MM(0,0,bF0); BARX();
    LOADB(bF1, 0,1);
    STAGEH(0, 0,0, A, m0, kA); STAGEH(65536, 0,0, B, n0, kA);
    BARX(); MM(0,1,bF1); BARX();
    LOADA(0,1);
    STAGEH(65536, 0,1, B, n0, kA);
    BARX(); MM(1,0,bF0); BARX();
    STAGEH(0, 0,1, A, m0, kA);
    VMW(8);
    BARX(); MM(1,1,bF1); BARX();
    LOADA(1,0); LOADB(bF0, 1,0);
    BARX(); MM(0,0,bF0); BARX();
    LOADB(bF1, 1,1);
    STAGEH(0, 1,0, A, m0, kB); STAGEH(65536, 1,0, B, n0, kB);
    BARX(); MM(0,1,bF1); BARX();
    LOADA(1,1);
    STAGEH(65536, 1,1, B, n0, kB);
    BARX(); MM(1,0,bF0); BARX();
    STAGEH(0, 1,1, A, m0, kB);
    VMW(8);
    BARX(); MM(1,1,bF1); BARX();
  }
  LOADA(0,0); LOADB(bF0, 0,0);
  BARX(); MM(0,0,bF0); BARX();
  LOADB(bF1, 0,1);
  BARX(); MM(0,1,bF1); BARX();
  LOADA(0,1);
  BARX(); MM(1,0,bF0); BARX();
  VMW(0);
  BARX(); MM(1,1,bF1); BARX();
  LOADA(1,0); LOADB(bF0, 1,0);
  BARX(); MM(0,0,bF0); BARX();
  LOADB(bF1, 1,1);
  BARX(); MM(0,1,bF1); BARX();
  LOADA(1,1);
  BARX(); MM(1,0,bF0); BARX();
  BARX(); MM(1,1,bF1); BARX();

  const int crow = lhi * 4;
#pragma unroll
  for (int mh = 0; mh < 2; ++mh)
#pragma unroll
    for (int nh = 0; nh < 2; ++nh)
#pragma unroll
      for (int m_ = 0; m_ < 4; ++m_)
#pragma unroll
        for (int n_ = 0; n_ < 2; ++n_) {
          float* cp = C + (size_t)(m0 + mh*128 + wm*64 + m_*16 + crow) * DIM
                        + (n0 + nh*128 + wn*32 + n_*16 + l15);
#pragma unroll
          for (int j2 = 0; j2 < 4; ++j2)
            cp[(size_t)j2 * DIM] = acc[mh][nh][m_][n_][j2];
        }
}

// ---------------- launch -------------------------------------------------------
extern "C" void kernel_launch(void* const* d_in, const int* in_sizes, int n_in,
                              void* d_out, int out_size, void* d_ws, size_t ws_size,
                              hipStream_t stream) {
  const float* x    = (const float*)d_in[0];
  const float* qry  = (const float*)d_in[1];
  const float* kvs  = (const float*)d_in[2];
  const float* wout = (const float*)d_in[3];
  float* out = (float*)d_out;

  char* ws = (char*)d_ws;
  size_t off = 0;
  uint4* spec = (uint4*)(ws + off);                     // 67.4 MB
  off += (size_t)ROWS * SPEC_STRIDE * sizeof(uint4);
  off = (off + 255) & ~(size_t)255;
  unsigned short* vbf = (unsigned short*)(ws + off);    // 67 MB
  off += (size_t)ROWS * DIM * sizeof(unsigned short);
  off = (off + 255) & ~(size_t)255;
  unsigned short* wbf = (unsigned short*)(ws + off);    // 8.4 MB
  off += (size_t)DIM * DIM * sizeof(unsigned short);
  off = (off + 255) & ~(size_t)255;
  float2* partial = (float2*)(ws + off);                // 8.4 MB
  off += (size_t)BATCH * NSC * NFREQ * sizeof(float2);
  off = (off + 255) & ~(size_t)255;
  float2* gtot = (float2*)(ws + off);                   // 0.5 MB
  off += (size_t)BATCH * NGRP * NFREQ * sizeof(float2);

  hipLaunchKernelGGL(w_to_bf16, dim3((DIM*DIM)/(256*4)), dim3(256), 0, stream, wout, wbf);
  hipLaunchKernelGGL(fwd_fused, dim3(BATCH*NSC),         dim3(256), 0, stream, x, kvs, spec, partial);
  hipLaunchKernelGGL(scanA,     dim3(BATCH*NGRP*5),      dim3(256), 0, stream, partial, gtot);
  hipLaunchKernelGGL(scanB,     dim3(BATCH*5),           dim3(256), 0, stream, gtot);
  hipLaunchKernelGGL(inv_fused, dim3(BATCH*NSC),         dim3(256), 0, stream, spec, kvs, qry, partial, gtot, vbf);
  hipLaunchKernelGGL(gemm256,   dim3((ROWS/256)*(DIM/256)), dim3(512), 0, stream, vbf, wbf, out);
}

// Round 6
// 222.853 us; speedup vs baseline: 2.1097x; 1.1153x over previous
//
#include <hip/hip_runtime.h>
#include <hip/hip_bf16.h>
#include <stdint.h>

#define BATCH 4
#define SEQ   4096
#define DIM   2048
#define NFREQ 1025
#define NCPLX 1024
#define ROWS  (BATCH*SEQ)   // 16384

// fused chunk decomposition
#define SCH  16            // rows per block (sequential, cumsum in regs)
#define NSC  (SEQ/SCH)     // 256 chunks per batch
#define NSCG 16            // chunks per scan group
#define NGRP (NSC/NSCG)    // 16 groups

#define SPEC_STRIDE 257    // uint4 per row: 256 pair-packed + 1 extra (k=512)

typedef __bf16 bf16x8 __attribute__((ext_vector_type(8)));
typedef float  f32x4  __attribute__((ext_vector_type(4)));

__device__ __forceinline__ int drev4(int n) {  // reverse 5 base-4 digits of 10-bit n
  return ((n&3)<<8) | (((n>>2)&3)<<6) | (((n>>4)&3)<<4) | (((n>>6)&3)<<2) | ((n>>8)&3);
}
#define ZI(i) ((i) + ((i)>>4))   // LDS pad: every 16 float2 -> +1 (caps conflicts ~4-way)

__device__ __forceinline__ float2 cmulf(float2 a, float2 b) {
  return make_float2(a.x*b.x - a.y*b.y, a.x*b.y + a.y*b.x);
}

__device__ __forceinline__ unsigned short f2bf(float f) {
  union { float f; unsigned u; } v; v.f = f;
  unsigned r = v.u + 0x7fffu + ((v.u >> 16) & 1u);
  return (unsigned short)(r >> 16);
}
__device__ __forceinline__ unsigned packbf(float2 v) {
  return (unsigned)f2bf(v.x) | ((unsigned)f2bf(v.y) << 16);
}
__device__ __forceinline__ float2 unpackbf(unsigned u) {
  union { unsigned u; float f; } a, b;
  a.u = u << 16; b.u = u & 0xffff0000u;
  return make_float2(a.f, b.f);
}

// ---------------- radix-4 1024-pt in-place DIT, precomputed stage twiddles ----
template<int INV>
__device__ __forceinline__ void fft_stages_tw(float2* z, int tid, const float2* tw1) {
  { // stage q=1 (no twiddles)
    int b4 = tid*4;
    float2 x0=z[ZI(b4)], x1=z[ZI(b4+1)], x2=z[ZI(b4+2)], x3=z[ZI(b4+3)];
    float2 a = make_float2(x0.x+x2.x, x0.y+x2.y), b = make_float2(x0.x-x2.x, x0.y-x2.y);
    float2 c = make_float2(x1.x+x3.x, x1.y+x3.y), d = make_float2(x1.x-x3.x, x1.y-x3.y);
    z[ZI(b4)]   = make_float2(a.x+c.x, a.y+c.y);
    z[ZI(b4+2)] = make_float2(a.x-c.x, a.y-c.y);
    if (!INV) { z[ZI(b4+1)] = make_float2(b.x+d.y, b.y-d.x);
                z[ZI(b4+3)] = make_float2(b.x-d.y, b.y+d.x); }
    else      { z[ZI(b4+1)] = make_float2(b.x-d.y, b.y+d.x);
                z[ZI(b4+3)] = make_float2(b.x+d.y, b.y-d.x); }
  }
  __syncthreads();
#pragma unroll
  for (int s = 0; s < 4; ++s) {
    const int lq = 2 + 2*s;          // q = 4,16,64,256
    const int q  = 1 << lq;
    int j = tid & (q-1), g = tid >> lq;
    int base = (g << (lq+2)) + j;
    float2 w1 = tw1[s]; if (INV) w1.y = -w1.y;
    float2 w2 = cmulf(w1, w1), w3 = cmulf(w2, w1);
    float2 x0 = z[ZI(base)];
    float2 x1 = cmulf(z[ZI(base+q)],   w1);
    float2 x2 = cmulf(z[ZI(base+2*q)], w2);
    float2 x3 = cmulf(z[ZI(base+3*q)], w3);
    float2 a = make_float2(x0.x+x2.x, x0.y+x2.y), b = make_float2(x0.x-x2.x, x0.y-x2.y);
    float2 c = make_float2(x1.x+x3.x, x1.y+x3.y), d = make_float2(x1.x-x3.x, x1.y-x3.y);
    z[ZI(base)]     = make_float2(a.x+c.x, a.y+c.y);
    z[ZI(base+2*q)] = make_float2(a.x-c.x, a.y-c.y);
    if (!INV) { z[ZI(base+q)]   = make_float2(b.x+d.y, b.y-d.x);
                z[ZI(base+3*q)] = make_float2(b.x-d.y, b.y+d.x); }
    else      { z[ZI(base+q)]   = make_float2(b.x-d.y, b.y+d.x);
                z[ZI(base+3*q)] = make_float2(b.x+d.y, b.y-d.x); }
    __syncthreads();
  }
}

__device__ __forceinline__ void make_tw1(int tid, float2* tw1) {
#pragma unroll
  for (int s = 0; s < 4; ++s) {
    const int lq = 2 + 2*s;
    const int q  = 1 << lq;
    int j = tid & (q-1);
    float ang = -6.2831853071795864769f * (float)j / (float)(4*q);
    float sw, cw; __sincosf(ang, &sw, &cw);
    tw1[s] = make_float2(cw, sw);
  }
}

// ============ fwd_fused: FFT 16 rows, store bf16 spectrum + kv partial sums ===
// Pair-packed spectrum: spec[row][t] = {v[t], v[1024-t], v[t+256], v[768-t]}
// (bf16 complex each); extra slot [256].x = v[512].
__global__ __launch_bounds__(256) void fwd_fused(const float* __restrict__ x,
                                                 const float* __restrict__ kvs,
                                                 uint4* __restrict__ spec,
                                                 float2* __restrict__ partial) {
  __shared__ float2 z[ZI(1023)+2];
  const int tid = threadIdx.x;
  const int sc = blockIdx.x & (NSC-1), b = blockIdx.x >> 8;

  float2 tw1[4];
  make_tw1(tid, tw1);
  const int kA = tid, kB = tid + 256;
  float swA, cwA, swB, cwB;   // w = e^{-i pi k/1024}
  __sincosf(-3.14159265358979323846f * (float)kA / 1024.0f, &swA, &cwA);
  __sincosf(-3.14159265358979323846f * (float)kB / 1024.0f, &swB, &cwB);
  int id0 = ZI(drev4(2*tid)),     id1 = ZI(drev4(2*tid+1));
  int id2 = ZI(drev4(2*tid+512)), id3 = ZI(drev4(2*tid+513));

  float2 sA={0,0}, sAp={0,0}, sB={0,0}, sBp={0,0}, s5={0,0};

  const size_t row0 = (size_t)b*SEQ + (size_t)sc*SCH;
  const float* xrow = x + row0*DIM;
  float4 c0 = ((const float4*)xrow)[tid];
  float4 c1 = ((const float4*)xrow)[tid + 256];

  for (int s = 0; s < SCH; ++s) {
    float4 n0f, n1f;
    if (s+1 < SCH) {
      const float* nx = xrow + (size_t)(s+1)*DIM;
      n0f = ((const float4*)nx)[tid]; n1f = ((const float4*)nx)[tid + 256];
    }
    z[id0] = make_float2(c0.x, c0.y); z[id1] = make_float2(c0.z, c0.w);
    z[id2] = make_float2(c1.x, c1.y); z[id3] = make_float2(c1.z, c1.w);
    __syncthreads();
    fft_stages_tw<0>(z, tid, tw1);
    float2 ZkA = z[ZI(kA)], ZnA = z[ZI((NCPLX - kA) & (NCPLX-1))];
    float2 ZkB = z[ZI(kB)], ZnB = z[ZI(768 - tid)];
    // pair unpack A: v[kA], v[1024-kA]
    float Er = 0.5f*(ZkA.x + ZnA.x), Ei = 0.5f*(ZkA.y - ZnA.y);
    float dr = 0.5f*(ZkA.x - ZnA.x), di = 0.5f*(ZkA.y + ZnA.y);
    float2 vA  = make_float2( Er + cwA*di + swA*dr,  Ei + swA*di - cwA*dr);
    float2 vAp = make_float2( Er - cwA*di - swA*dr, -Ei + swA*di - cwA*dr);
    // pair unpack B: v[kB], v[768-tid]
    float Fr = 0.5f*(ZkB.x + ZnB.x), Fi = 0.5f*(ZkB.y - ZnB.y);
    float er = 0.5f*(ZkB.x - ZnB.x), ei = 0.5f*(ZkB.y + ZnB.y);
    float2 vB  = make_float2( Fr + cwB*ei + swB*er,  Fi + swB*ei - cwB*er);
    float2 vBp = make_float2( Fr - cwB*ei - swB*er, -Fi + swB*ei - cwB*er);
    sA.x += vA.x;  sA.y += vA.y;   sAp.x += vAp.x; sAp.y += vAp.y;
    sB.x += vB.x;  sB.y += vB.y;   sBp.x += vBp.x; sBp.y += vBp.y;
    uint4* sprow = spec + (row0 + s) * SPEC_STRIDE;
    sprow[tid] = make_uint4(packbf(vA), packbf(vAp), packbf(vB), packbf(vBp));
    if (tid == 0) {
      float2 Z5 = z[ZI(512)];
      float2 v5 = make_float2(Z5.x, -Z5.y);
      s5.x += v5.x; s5.y += v5.y;
      ((unsigned*)(sprow + 256))[0] = packbf(v5);
    }
    __syncthreads();                                   // z free for next scatter
    c0 = n0f; c1 = n1f;
  }
  float2* pp = partial + ((size_t)(b*NSC + sc)) * NFREQ;
  float kvA = kvs[kA], kvAp = kvs[NCPLX - kA], kvB = kvs[kB], kvBp = kvs[768 - tid];
  pp[kA]          = make_float2(kvA*sA.x,  kvA*sA.y);
  pp[NCPLX - kA]  = make_float2(kvAp*sAp.x, kvAp*sAp.y);
  pp[kB]          = make_float2(kvB*sB.x,  kvB*sB.y);
  pp[768 - tid]   = make_float2(kvBp*sBp.x, kvBp*sBp.y);
  if (tid == 0) { float kv5 = kvs[512]; pp[512] = make_float2(kv5*s5.x, kv5*s5.y); }
}

// ============ wfft: H[e,:] = spectral-domain weight row (bf16) ================
// H[e,k]      = alpha_k * Re(rfft(W[e,:]))[k],   k = 0..1024
// H[e,1024+j] = (2/N)   * Im(rfft(W[e,:]))[j],   j = 1..1023
// alpha = 1/N at k in {0,1024}, else 2/N. Then out = G @ H^T == irfft(qv) @ W^T.
__global__ __launch_bounds__(256) void wfft(const float* __restrict__ w,
                                            unsigned short* __restrict__ H) {
  __shared__ float2 z[ZI(1023)+2];
  __shared__ __align__(16) unsigned short hrow[2048];
  const int tid = threadIdx.x;
  const int e = blockIdx.x;

  float2 tw1[4];
  make_tw1(tid, tw1);
  const int kB = tid + 256;
  float swA, cwA, swB, cwB;
  __sincosf(-3.14159265358979323846f * (float)tid / 1024.0f, &swA, &cwA);
  __sincosf(-3.14159265358979323846f * (float)kB  / 1024.0f, &swB, &cwB);
  int id0 = ZI(drev4(2*tid)),     id1 = ZI(drev4(2*tid+1));
  int id2 = ZI(drev4(2*tid+512)), id3 = ZI(drev4(2*tid+513));

  const float* wr = w + (size_t)e * DIM;
  float4 c0 = ((const float4*)wr)[tid];
  float4 c1 = ((const float4*)wr)[tid + 256];
  z[id0] = make_float2(c0.x, c0.y); z[id1] = make_float2(c0.z, c0.w);
  z[id2] = make_float2(c1.x, c1.y); z[id3] = make_float2(c1.z, c1.w);
  __syncthreads();
  fft_stages_tw<0>(z, tid, tw1);

  float2 ZkA = z[ZI(tid)], ZnA = z[ZI((NCPLX - tid) & (NCPLX-1))];
  float2 ZkB = z[ZI(kB)],  ZnB = z[ZI(768 - tid)];
  float Er = 0.5f*(ZkA.x + ZnA.x), Ei = 0.5f*(ZkA.y - ZnA.y);
  float dr = 0.5f*(ZkA.x - ZnA.x), di = 0.5f*(ZkA.y + ZnA.y);
  float2 vA  = make_float2( Er + cwA*di + swA*dr,  Ei + swA*di - cwA*dr);
  float2 vAp = make_float2( Er - cwA*di - swA*dr, -Ei + swA*di - cwA*dr);
  float Fr = 0.5f*(ZkB.x + ZnB.x), Fi = 0.5f*(ZkB.y - ZnB.y);
  float er = 0.5f*(ZkB.x - ZnB.x), ei = 0.5f*(ZkB.y + ZnB.y);
  float2 vB  = make_float2( Fr + cwB*ei + swB*er,  Fi + swB*ei - cwB*er);
  float2 vBp = make_float2( Fr - cwB*ei - swB*er, -Fi + swB*ei - cwB*er);

  const float invN = 1.0f/2048.0f, twoN = 2.0f/2048.0f;
  float aA  = (tid == 0) ? invN : twoN;   // k=0 at tid 0
  float aAp = (tid == 0) ? invN : twoN;   // k=1024 at tid 0
  hrow[tid]        = f2bf(aA  * vA.x);
  hrow[1024 - tid] = f2bf(aAp * vAp.x);
  hrow[256 + tid]  = f2bf(twoN * vB.x);
  hrow[768 - tid]  = f2bf(twoN * vBp.x);
  if (tid) {
    hrow[1024 + tid] = f2bf(twoN * vA.y);
    hrow[2048 - tid] = f2bf(twoN * vAp.y);
  }
  hrow[1280 + tid] = f2bf(twoN * vB.y);
  hrow[1792 - tid] = f2bf(twoN * vBp.y);
  if (tid == 0) {
    float2 Z5 = z[ZI(512)];
    hrow[512]  = f2bf(twoN * Z5.x);
    hrow[1536] = f2bf(twoN * (-Z5.y));
  }
  __syncthreads();
  ((uint4*)(H + (size_t)e * DIM))[tid] = ((const uint4*)hrow)[tid];
}

// ============ 2-level chunk scan ==============================================
__global__ __launch_bounds__(256) void scanA(float2* __restrict__ partial,
                                             float2* __restrict__ gtot) {
  int kc = blockIdx.x % 5, g = (blockIdx.x / 5) % NGRP, b = blockIdx.x / (5*NGRP);
  int k = kc*256 + threadIdx.x;
  if (k >= NFREQ) return;
  float2* p = partial + ((size_t)(b*NSC + g*NSCG)) * NFREQ + k;
  float2 run = {0.f, 0.f};
#pragma unroll
  for (int i = 0; i < NSCG; ++i) {
    float2 t = p[(size_t)i*NFREQ];
    p[(size_t)i*NFREQ] = run;                          // exclusive within group
    run.x += t.x; run.y += t.y;
  }
  gtot[((size_t)(b*NGRP + g)) * NFREQ + k] = run;
}

__global__ __launch_bounds__(256) void scanB(float2* __restrict__ gtot) {
  int kc = blockIdx.x % 5, b = blockIdx.x / 5;
  int k = kc*256 + threadIdx.x;
  if (k >= NFREQ) return;
  float2* p = gtot + ((size_t)b*NGRP) * NFREQ + k;
  float2 run = {0.f, 0.f};
#pragma unroll
  for (int g = 0; g < NGRP; ++g) {
    float2 t = p[(size_t)g*NFREQ];
    p[(size_t)g*NFREQ] = run;                          // exclusive across groups
    run.x += t.x; run.y += t.y;
  }
}

// ============ inv_fused: cumsum-apply -> spectral G rows (bf16), NO irfft =====
// G[row, k]      = qv_r[k]  (k = 0..1024)
// G[row, 1024+j] = qv_i[j]  (j = 1..1023)
__global__ __launch_bounds__(256) void inv_fused(const uint4* __restrict__ spec,
                                                 const float* __restrict__ kvs,
                                                 const float* __restrict__ qs_,
                                                 const float2* __restrict__ partial,
                                                 const float2* __restrict__ gtot,
                                                 unsigned short* __restrict__ G) {
  __shared__ __align__(16) unsigned short grow[2048];
  const int tid = threadIdx.x;
  const int sc = blockIdx.x & (NSC-1), b = blockIdx.x >> 8;
  const int kA = tid, kB = tid + 256;

  float ksA = kvs[kA], ksAp = kvs[NCPLX - kA], ksB = kvs[kB], ksBp = kvs[768 - tid];
  float qsA = qs_[kA], qsAp = qs_[NCPLX - kA], qsB = qs_[kB], qsBp = qs_[768 - tid];

  const float2* pp = partial + ((size_t)(b*NSC + sc)) * NFREQ;
  const float2* gp = gtot + ((size_t)(b*NGRP + (sc >> 4))) * NFREQ;
  float2 CA  = make_float2(pp[kA].x + gp[kA].x,                 pp[kA].y + gp[kA].y);
  float2 CAp = make_float2(pp[NCPLX-kA].x + gp[NCPLX-kA].x,     pp[NCPLX-kA].y + gp[NCPLX-kA].y);
  float2 CB  = make_float2(pp[kB].x + gp[kB].x,                 pp[kB].y + gp[kB].y);
  float2 CBp = make_float2(pp[768-tid].x + gp[768-tid].x,       pp[768-tid].y + gp[768-tid].y);
  float ks5 = kvs[512], qs5 = qs_[512];
  float2 C5 = make_float2(pp[512].x + gp[512].x, pp[512].y + gp[512].y);

  const size_t row0 = (size_t)b*SEQ + (size_t)sc*SCH;
  const uint4* sprow = spec + row0 * SPEC_STRIDE;
  uint4 sp = sprow[tid];
  unsigned spN = ((const unsigned*)(sprow + 256))[0];

  for (int s = 0; s < SCH; ++s) {
    uint4 spn; unsigned spNn;
    if (s+1 < SCH) {
      const uint4* nr = sprow + (size_t)(s+1) * SPEC_STRIDE;
      spn = nr[tid]; spNn = ((const unsigned*)(nr + 256))[0];
    }
    float2 vA = unpackbf(sp.x), vAp = unpackbf(sp.y);
    float2 vB = unpackbf(sp.z), vBp = unpackbf(sp.w);
    CA.x  += vA.x*ksA;   CA.y  += vA.y*ksA;
    CAp.x += vAp.x*ksAp; CAp.y += vAp.y*ksAp;
    CB.x  += vB.x*ksB;   CB.y  += vB.y*ksB;
    CBp.x += vBp.x*ksBp; CBp.y += vBp.y*ksBp;
    float2 qvA  = make_float2(qsA *(vA.x*CA.x  - vA.y*CA.y),  qsA *(vA.x*CA.y  + vA.y*CA.x));
    float2 qvAp = make_float2(qsAp*(vAp.x*CAp.x- vAp.y*CAp.y),qsAp*(vAp.x*CAp.y+ vAp.y*CAp.x));
    float2 qvB  = make_float2(qsB *(vB.x*CB.x  - vB.y*CB.y),  qsB *(vB.x*CB.y  + vB.y*CB.x));
    float2 qvBp = make_float2(qsBp*(vBp.x*CBp.x- vBp.y*CBp.y),qsBp*(vBp.x*CBp.y+ vBp.y*CBp.x));
    // scatter spectral row: real cols {t,1024-t,256+t,768-t}, imag cols 1024+k
    grow[tid]        = f2bf(qvA.x);
    grow[1024 - tid] = f2bf(qvAp.x);
    grow[256 + tid]  = f2bf(qvB.x);
    grow[768 - tid]  = f2bf(qvBp.x);
    if (tid) {
      grow[1024 + tid] = f2bf(qvA.y);
      grow[2048 - tid] = f2bf(qvAp.y);
    }
    grow[1280 + tid] = f2bf(qvB.y);
    grow[1792 - tid] = f2bf(qvBp.y);
    if (tid == 0) {
      float2 v5 = unpackbf(spN);
      C5.x += v5.x*ks5; C5.y += v5.y*ks5;
      grow[512]  = f2bf(qs5*(v5.x*C5.x - v5.y*C5.y));
      grow[1536] = f2bf(qs5*(v5.x*C5.y + v5.y*C5.x));
    }
    __syncthreads();
    ((uint4*)(G + (row0 + s) * DIM))[tid] = ((const uint4*)grow)[tid];
    __syncthreads();
    sp = spn; spN = spNn;
  }
}

// ============ 256x256 8-phase GEMM: C[M,N] = A[M,K] * B[N,K]^T, bf16->fp32 =====
#define NKT (DIM/64)      // 32 K-tiles
#define NIT (NKT/2)       // 16 iterations of 2 K-tiles

#define BARX() do{ __builtin_amdgcn_s_barrier(); __builtin_amdgcn_sched_barrier(0); }while(0)
#define VMW(N) do{ asm volatile("s_waitcnt vmcnt(" #N ")" ::: "memory"); __builtin_amdgcn_sched_barrier(0); }while(0)

#define LOADA(B_, MH) do{ _Pragma("unroll") for (int m_=0;m_<4;++m_) _Pragma("unroll") for (int kk_=0;kk_<2;++kk_){ \
    int rA_ = wm*64 + m_*16 + l15; \
    aF[m_][kk_] = *(const bf16x8*)(smem + ((B_)*2+(MH))*16384 + rA_*128 + ((kk_*64 + lhi*16) ^ ((rA_&7)<<4))); } }while(0)

#define LOADB(DST, B_, NH) do{ _Pragma("unroll") for (int n_=0;n_<2;++n_) _Pragma("unroll") for (int kk_=0;kk_<2;++kk_){ \
    int rB_ = wn*32 + n_*16 + l15; \
    DST[n_][kk_] = *(const bf16x8*)(smem + 65536 + ((B_)*2+(NH))*16384 + rB_*128 + ((kk_*64 + lhi*16) ^ ((rB_&7)<<4))); } }while(0)

#define MM(MH, NH, BF) do{ __builtin_amdgcn_s_setprio(1); \
    _Pragma("unroll") for (int kk_=0;kk_<2;++kk_) _Pragma("unroll") for (int m_=0;m_<4;++m_) _Pragma("unroll") for (int n_=0;n_<2;++n_) \
      acc[MH][NH][m_][n_] = __builtin_amdgcn_mfma_f32_16x16x32_bf16(aF[m_][kk_], BF[n_][kk_], acc[MH][NH][m_][n_], 0, 0, 0); \
    __builtin_amdgcn_s_setprio(0); }while(0)

#define STAGEH(REG, B_, H_, GP, ROW0, KT) do{ _Pragma("unroll") for (int c_=0;c_<2;++c_){ \
    int ci_ = c_*512 + tid; int r_ = ci_>>3, sl_ = ci_&7; \
    const unsigned short* sp_ = (GP) + (size_t)((ROW0) + (H_)*128 + r_)*DIM + (KT) + ((sl_ ^ (r_&7))*8); \
    __builtin_amdgcn_global_load_lds((const __attribute__((address_space(1))) void*)sp_, \
      (__attribute__((address_space(3))) void*)(smem + (REG) + ((B_)*2+(H_))*16384 + ci_*16), 16, 0, 0); } }while(0)

__global__ __launch_bounds__(512, 2) void gemm256(const unsigned short* __restrict__ A,
                                                  const unsigned short* __restrict__ B,
                                                  float* __restrict__ C) {
  __shared__ __align__(16) char smem[131072];
  const int tid = threadIdx.x;
  const int lane = tid & 63;
  const int wid  = tid >> 6;
  const int wm = wid >> 2, wn = wid & 3;
  const int l15 = lane & 15, lhi = lane >> 4;

  // XCD-grouped swizzle: XCD j (= bid%8) owns bm in [8j, 8j+8) for all bn ->
  // A-panels fetched by exactly one XCD's L2; B panels (8 MB) L2/L3-resident.
  const int xj = blockIdx.x & 7, tt = blockIdx.x >> 3;
  const int bm = xj * 8 + (tt >> 3), bn = tt & 7;
  const int m0 = bm * 256, n0 = bn * 256;

  f32x4 acc[2][2][4][2] = {};
  bf16x8 aF[4][2], bF0[2][2], bF1[2][2];

  STAGEH(0,     0,0, A, m0, 0);  STAGEH(65536, 0,0, B, n0, 0);
  STAGEH(65536, 0,1, B, n0, 0);  STAGEH(0,     0,1, A, m0, 0);
  STAGEH(0,     1,0, A, m0, 64); STAGEH(65536, 1,0, B, n0, 64);
  STAGEH(65536, 1,1, B, n0, 64); STAGEH(0,     1,1, A, m0, 64);
  VMW(8);
  BARX();

#pragma unroll 1
  for (int j = 0; j < NIT-1; ++j) {
    const int kA = (2*j+2)*64, kB = (2*j+3)*64;
    LOADA(0,0); LOADB(bF0, 0,0);
    BARX(); MM(0,0,bF0); BARX();
    LOADB(bF1, 0,1);
    STAGEH(0, 0,0, A, m0, kA); STAGEH(65536, 0,0, B, n0, kA);
    BARX(); MM(0,1,bF1); BARX();
    LOADA(0,1);
    STAGEH(65536, 0,1, B, n0, kA);
    BARX(); MM(1,0,bF0); BARX();
    STAGEH(0, 0,1, A, m0, kA);
    VMW(8);
    BARX(); MM(1,1,bF1); BARX();
    LOADA(1,0); LOADB(bF0, 1,0);
    BARX(); MM(0,0,bF0); BARX();
    LOADB(bF1, 1,1);
    STAGEH(0, 1,0, A, m0, kB); STAGEH(65536, 1,0, B, n0, kB);
    BARX(); MM(0,1,bF1); BARX();
    LOADA(1,1);
    STAGEH(65536, 1,1, B, n0, kB);
    BARX(); MM(1,0,bF0); BARX();
    STAGEH(0, 1,1, A, m0, kB);
    VMW(8);
    BARX(); MM(1,1,bF1); BARX();
  }
  LOADA(0,0); LOADB(bF0, 0,0);
  BARX(); MM(0,0,bF0); BARX();
  LOADB(bF1, 0,1);
  BARX(); MM(0,1,bF1); BARX();
  LOADA(0,1);
  BARX(); MM(1,0,bF0); BARX();
  VMW(0);
  BARX(); MM(1,1,bF1); BARX();
  LOADA(1,0); LOADB(bF0, 1,0);
  BARX(); MM(0,0,bF0); BARX();
  LOADB(bF1, 1,1);
  BARX(); MM(0,1,bF1); BARX();
  LOADA(1,1);
  BARX(); MM(1,0,bF0); BARX();
  BARX(); MM(1,1,bF1); BARX();

  const int crow = lhi * 4;
#pragma unroll
  for (int mh = 0; mh < 2; ++mh)
#pragma unroll
    for (int nh = 0; nh < 2; ++nh)
#pragma unroll
      for (int m_ = 0; m_ < 4; ++m_)
#pragma unroll
        for (int n_ = 0; n_ < 2; ++n_) {
          float* cp = C + (size_t)(m0 + mh*128 + wm*64 + m_*16 + crow) * DIM
                        + (n0 + nh*128 + wn*32 + n_*16 + l15);
#pragma unroll
          for (int j2 = 0; j2 < 4; ++j2)
            cp[(size_t)j2 * DIM] = acc[mh][nh][m_][n_][j2];
        }
}

// ---------------- launch -------------------------------------------------------
extern "C" void kernel_launch(void* const* d_in, const int* in_sizes, int n_in,
                              void* d_out, int out_size, void* d_ws, size_t ws_size,
                              hipStream_t stream) {
  const float* x    = (const float*)d_in[0];
  const float* qry  = (const float*)d_in[1];
  const float* kvs  = (const float*)d_in[2];
  const float* wout = (const float*)d_in[3];
  float* out = (float*)d_out;

  char* ws = (char*)d_ws;
  size_t off = 0;
  uint4* spec = (uint4*)(ws + off);                     // 67.4 MB
  off += (size_t)ROWS * SPEC_STRIDE * sizeof(uint4);
  off = (off + 255) & ~(size_t)255;
  unsigned short* G = (unsigned short*)(ws + off);      // 67 MB (spectral A)
  off += (size_t)ROWS * DIM * sizeof(unsigned short);
  off = (off + 255) & ~(size_t)255;
  unsigned short* H = (unsigned short*)(ws + off);      // 8.4 MB (spectral W)
  off += (size_t)DIM * DIM * sizeof(unsigned short);
  off = (off + 255) & ~(size_t)255;
  float2* partial = (float2*)(ws + off);                // 8.4 MB
  off += (size_t)BATCH * NSC * NFREQ * sizeof(float2);
  off = (off + 255) & ~(size_t)255;
  float2* gtot = (float2*)(ws + off);                   // 0.5 MB
  off += (size_t)BATCH * NGRP * NFREQ * sizeof(float2);

  hipLaunchKernelGGL(wfft,      dim3(DIM),               dim3(256), 0, stream, wout, H);
  hipLaunchKernelGGL(fwd_fused, dim3(BATCH*NSC),         dim3(256), 0, stream, x, kvs, spec, partial);
  hipLaunchKernelGGL(scanA,     dim3(BATCH*NGRP*5),      dim3(256), 0, stream, partial, gtot);
  hipLaunchKernelGGL(scanB,     dim3(BATCH*5),           dim3(256), 0, stream, gtot);
  hipLaunchKernelGGL(inv_fused, dim3(BATCH*NSC),         dim3(256), 0, stream, spec, kvs, qry, partial, gtot, G);
  hipLaunchKernelGGL(gemm256,   dim3((ROWS/256)*(DIM/256)), dim3(512), 0, stream, G, H, out);
}